// Round 1
// baseline (3633.017 us; speedup 1.0000x reference)
//
#include <hip/hip_runtime.h>
#include <math.h>

#define NN 2048
#define NE 49152
#define WNUM 3328
#define N1c 1536
#define B3c 2304
#define B4c 2816
#define B5c 3072

__device__ __forceinline__ float silu_f(float x){ return x / (1.0f + expf(-x)); }
__device__ __forceinline__ float sigm_f(float x){ return 1.0f / (1.0f + expf(-x)); }

// ---------------- edge geometry: y1(3), Ay(9), rbf(8) -> egeo stride 20 ----------------
__global__ void geom_kernel(const float* __restrict__ pos, const int* __restrict__ ei,
                            float* __restrict__ egeo) {
  int e = blockIdx.x * 256 + threadIdx.x;
  if (e >= NE) return;
  int s = ei[e], d = ei[NE + e];
  float rx = pos[d*3+0] - pos[s*3+0];
  float ry = pos[d*3+1] - pos[s*3+1];
  float rz = pos[d*3+2] - pos[s*3+2];
  float r = sqrtf(rx*rx + ry*ry + rz*rz);
  r = fmaxf(r, 1e-6f);
  float x = rx / r, y = ry / r, z = rz / r;
  const float s3 = 1.7320508075688772f;   // sqrt(3)
  const float c15 = 3.872983346207417f;   // sqrt(15)
  float y2_0 = c15 * x * y;
  float y2_1 = c15 * y * z;
  float y2_2 = 1.118033988749895f * (3.0f*z*z - 1.0f); // 0.5*sqrt(5)
  float y2_3 = c15 * x * z;
  float y2_4 = 1.9364916731037085f * (x*x - y*y);      // 0.5*sqrt(15)
  const float q2 = 0.7071067811865476f;  // 1/sqrt(2)
  const float q6 = 0.4082482904638631f;  // 1/sqrt(6)
  float* g = egeo + (size_t)e * 20;
  g[0] = s3 * x; g[1] = s3 * y; g[2] = s3 * z;
  // Ay[i][j] = sum_m y2[m] * Q2[m][i][j]
  g[3+0] = -q6*y2_2 + q2*y2_4;  // 00
  g[3+1] =  q2*y2_0;            // 01
  g[3+2] =  q2*y2_3;            // 02
  g[3+3] =  q2*y2_0;            // 10
  g[3+4] = -q6*y2_2 - q2*y2_4;  // 11
  g[3+5] =  q2*y2_1;            // 12
  g[3+6] =  q2*y2_3;            // 20
  g[3+7] =  q2*y2_1;            // 21
  g[3+8] =  2.0f*q6*y2_2;       // 22
  float u = r / 6.0f;
  float fc = 0.0f;
  if (u < 1.0f) {
    float u2=u*u, u3=u2*u, u6=u3*u3, u7=u6*u, u8=u7*u;
    fc = 1.0f - 28.0f*u6 + 48.0f*u7 - 21.0f*u8;
  }
  const float pref = 0.5773502691896258f; // sqrt(2/6)
  const float pi6 = 0.5235987755982988f;  // pi/6
  #pragma unroll
  for (int n = 1; n <= 8; n++) {
    g[12 + n - 1] = pref * sinf((float)n * pi6 * r) / r * fc;
  }
}

// ---------------- embed: h[:, :32] = x@embed_w/4, rest 0 ----------------
__global__ void embed_kernel(const float* __restrict__ x, const float* __restrict__ ew,
                             float* __restrict__ h) {
  int idx = blockIdx.x * 256 + threadIdx.x;
  if (idx >= NN * 80) return;
  int n = idx / 80, c = idx % 80;
  float v = 0.0f;
  if (c < 32) {
    #pragma unroll
    for (int j = 0; j < 16; j++) v += x[n*16 + j] * ew[j*32 + c];
    v *= 0.25f;
  }
  h[idx] = v;
}

// ---------------- radial MLP: f = silu(silu(rbf@W1+b1)@W2+b2), per layer ----------------
__global__ void radial_kernel(const float* __restrict__ egeo,
                              const float* __restrict__ w1, const float* __restrict__ b1,
                              const float* __restrict__ w2, const float* __restrict__ b2,
                              float* __restrict__ f, int l) {
  __shared__ float h1[4][64];
  int ty = threadIdx.x >> 6, dk = threadIdx.x & 63;
  int e = blockIdx.x * 4 + ty;
  const float* w1l = w1 + (size_t)l * 8 * 64;
  const float* w2l = w2 + (size_t)l * 64 * 64;
  float acc = b1[l*64 + dk];
  const float* rb = egeo + (size_t)e * 20 + 12;
  #pragma unroll
  for (int j = 0; j < 8; j++) acc += rb[j] * w1l[j*64 + dk];
  h1[ty][dk] = silu_f(acc);
  __syncthreads();
  float acc2 = b2[l*64 + dk];
  #pragma unroll 8
  for (int j = 0; j < 64; j++) acc2 += h1[ty][j] * w2l[j*64 + dk];
  f[(size_t)e*64 + dk] = silu_f(acc2);
}

// ---------------- node linears: hx (lin_*) and x_self (sc_*) ----------------
__global__ void node_lin_kernel(const float* __restrict__ h,
                                const float* __restrict__ lws, const float* __restrict__ lwv,
                                const float* __restrict__ sws, const float* __restrict__ swv,
                                float* __restrict__ hx, float* __restrict__ xself, int l) {
  int idx = blockIdx.x * 256 + threadIdx.x;
  if (idx >= NN * 160) return;
  int which = (idx >= NN * 80) ? 1 : 0;
  int r = which ? idx - NN*80 : idx;
  int n = r / 80, c = r % 80;
  const float* Ws = (which ? sws : lws) + (size_t)l * 1024;
  const float* Wv = (which ? swv : lwv) + (size_t)l * 256;
  float v = 0.0f;
  if (c < 32) {
    #pragma unroll 8
    for (int u = 0; u < 32; u++) v += h[n*80 + u] * Ws[u*32 + c];
    v *= 0.17677669529663687f;  // 1/sqrt(32)
  } else {
    int oc = c - 32, wch = oc / 3, i = oc % 3;
    #pragma unroll
    for (int u = 0; u < 16; u++) v += h[n*80 + 32 + u*3 + i] * Wv[u*16 + wch];
    v *= 0.25f;                 // 1/sqrt(16)
  }
  (which ? xself : hx)[n*80 + c] = v;
}

// ---------------- fused per-edge weight GEMM + tensor-product + aggregate ----------------
__launch_bounds__(256)
__global__ void edge_msg_kernel(const int* __restrict__ ei, const float* __restrict__ egeo,
                                const float* __restrict__ f, const float* __restrict__ hx,
                                const float* __restrict__ w3g, const float* __restrict__ b3g,
                                float* __restrict__ agg, int l) {
  __shared__ float s_ft[64][36];   // f transposed [k][e], 32 edges
  __shared__ float s_s[32][32];
  __shared__ float s_p2[32][16];
  __shared__ float s_v[32][48];
  __shared__ float s_q5[32][48];
  __shared__ float s_y1[32][4];
  __shared__ float s_w3[64][96];   // staged W3 slice (<=96 cols)
  __shared__ float s_wb[32][96];   // computed w values

  int t = threadIdx.x;
  int g0 = blockIdx.x * 32;
  const float* w3l = w3g + (size_t)l * 64 * WNUM;
  const float* b3l = b3g + (size_t)l * WNUM;

  // load f transposed (float4 along k, scatter)
  #pragma unroll
  for (int rr = 0; rr < 2; rr++) {
    int idx = t + 256 * rr;
    int e = idx >> 4, k4 = (idx & 15) * 4;
    float4 fv = *(const float4*)&f[(size_t)(g0 + e) * 64 + k4];
    s_ft[k4+0][e] = fv.x; s_ft[k4+1][e] = fv.y; s_ft[k4+2][e] = fv.z; s_ft[k4+3][e] = fv.w;
  }
  // gather hx[src] features
  for (int idx = t; idx < 32*80; idx += 256) {
    int e = idx / 80, c = idx % 80;
    int src = ei[g0 + e];
    float v = hx[(size_t)src*80 + c];
    if (c < 32) s_s[e][c] = v; else s_v[e][c-32] = v;
  }
  if (t < 96) { int e = t / 3, i = t % 3; s_y1[e][i] = egeo[(size_t)(g0+e)*20 + i]; }
  __syncthreads();
  // p2[u] = sum_i v[u,i]*y1[i]/sqrt(3)
  if (t < 512) {
    int e = t >> 4, u = t & 15;
    float acc = 0.0f;
    #pragma unroll
    for (int i = 0; i < 3; i++) acc += s_v[e][u*3+i] * s_y1[e][i];
    s_p2[e][u] = acc * 0.5773502691896258f;
  }
  // q5[u,j] = sqrt(3/5)*sum_i v[u,i]*Ay[i][j]
  for (int idx = t; idx < 32*48; idx += 256) {
    int e = idx / 48, o = idx % 48, u = o / 3, j = o % 3;
    const float* Ay = &egeo[(size_t)(g0+e)*20 + 3];
    float acc = 0.0f;
    #pragma unroll
    for (int i = 0; i < 3; i++) acc += s_v[e][u*3+i] * Ay[i*3 + j];
    s_q5[e][o] = acc * 0.7745966692414834f;
  }
  __syncthreads();

  float macc[12];
  #pragma unroll
  for (int j = 0; j < 12; j++) macc[j] = 0.0f;
  int e_own = t >> 3, o0 = (t & 7) * 12;

  for (int rd = 0; rd < 36; rd++) {
    int type, u0, G, gw, base;
    if (rd < 16)      { type = 1; u0 = rd*2;        G = 2; gw = 48; base = u0*48; }
    else if (rd < 24) { type = 2; u0 = (rd-16)*2;   G = 2; gw = 48; base = N1c + u0*48; }
    else if (rd < 30) { type = 3; u0 = (rd-24)*6;   G = (32-u0 < 6) ? 32-u0 : 6; gw = 16; base = B3c + u0*16; }
    else if (rd < 33) { type = 4; u0 = (rd-30)*6;   G = (16-u0 < 6) ? 16-u0 : 6; gw = 16; base = B4c + u0*16; }
    else              { type = 5; u0 = (rd-33)*6;   G = (16-u0 < 6) ? 16-u0 : 6; gw = 16; base = B5c + u0*16; }
    int NC = G * gw;
    int c4s = NC >> 2;
    // stage W3 slice
    for (int idx = t; idx < 64 * c4s; idx += 256) {
      int row = idx / c4s, c4 = idx % c4s;
      *(float4*)&s_w3[row][c4*4] = *(const float4*)&w3l[(size_t)row * WNUM + base + c4*4];
    }
    __syncthreads();
    // compute wb = f @ W3slice + b3  (microtile 4e x 4c, rank-1 over k)
    {
      int et = t / c4s, ct = t % c4s;
      if (et < 8) {
        float acc[4][4];
        #pragma unroll
        for (int a = 0; a < 4; a++)
          #pragma unroll
          for (int b = 0; b < 4; b++) acc[a][b] = 0.0f;
        for (int k4 = 0; k4 < 16; k4++) {
          #pragma unroll
          for (int kk = 0; kk < 4; kk++) {
            int k = k4*4 + kk;
            float4 fv = *(const float4*)&s_ft[k][et*4];
            float4 wv = *(const float4*)&s_w3[k][ct*4];
            acc[0][0] += fv.x*wv.x; acc[0][1] += fv.x*wv.y; acc[0][2] += fv.x*wv.z; acc[0][3] += fv.x*wv.w;
            acc[1][0] += fv.y*wv.x; acc[1][1] += fv.y*wv.y; acc[1][2] += fv.y*wv.z; acc[1][3] += fv.y*wv.w;
            acc[2][0] += fv.z*wv.x; acc[2][1] += fv.z*wv.y; acc[2][2] += fv.z*wv.z; acc[2][3] += fv.z*wv.w;
            acc[3][0] += fv.w*wv.x; acc[3][1] += fv.w*wv.y; acc[3][2] += fv.w*wv.z; acc[3][3] += fv.w*wv.w;
          }
        }
        float4 bb = *(const float4*)&b3l[base + ct*4];
        #pragma unroll
        for (int a = 0; a < 4; a++) {
          float4 ov; ov.x = acc[a][0]+bb.x; ov.y = acc[a][1]+bb.y; ov.z = acc[a][2]+bb.z; ov.w = acc[a][3]+bb.w;
          *(float4*)&s_wb[et*4 + a][ct*4] = ov;
        }
      }
    }
    __syncthreads();
    // contract into owned msg accumulators
    if (type <= 2) {
      if (o0 < 48) {
        for (int g = 0; g < G; g++) {
          float m = (type == 1) ? s_s[e_own][u0+g] : s_p2[e_own][u0+g];
          #pragma unroll
          for (int j = 0; j < 12; j++) macc[j] += m * s_wb[e_own][g*48 + o0 + j];
        }
      }
    } else {
      if (o0 >= 48) {
        #pragma unroll
        for (int j = 0; j < 12; j++) {
          int oc = o0 - 48 + j, wch = oc / 3, i = oc % 3;
          for (int g = 0; g < G; g++) {
            float m;
            if (type == 3)      m = s_s[e_own][u0+g] * s_y1[e_own][i];
            else if (type == 4) m = s_v[e_own][(u0+g)*3 + i];
            else                m = s_q5[e_own][(u0+g)*3 + i];
            macc[j] += m * s_wb[e_own][g*16 + wch];
          }
        }
      }
    }
    __syncthreads();
  }

  // epilogue: scale + atomic scatter to agg[dst]
  int ge = g0 + e_own;
  int dst = ei[NE + ge];
  float sc = (o0 < 48) ? (0.14433756729740645f * 0.20412414523193154f)
                       : (0.125f * 0.20412414523193154f);
  #pragma unroll
  for (int j = 0; j < 12; j++) {
    atomicAdd(&agg[(size_t)dst*96 + o0 + j], macc[j] * sc);
  }
}

// ---------------- node update: h += x_self + [silu(agg_s), sigmoid(g)*vec] ----------------
__global__ void node_update_kernel(const float* __restrict__ agg, const float* __restrict__ xself,
                                   float* __restrict__ h) {
  int idx = blockIdx.x * 256 + threadIdx.x;
  if (idx >= NN * 80) return;
  int n = idx / 80, c = idx % 80;
  float a;
  if (c < 32) {
    a = silu_f(agg[(size_t)n*96 + c]);
  } else {
    int oc = c - 32, wch = oc / 3;
    float gg = sigm_f(agg[(size_t)n*96 + 32 + wch]);
    a = agg[(size_t)n*96 + 48 + oc] * gg;
  }
  h[idx] = h[idx] + xself[idx] + a;
}

// ---------------- final projection ----------------
__global__ void proj_kernel(const float* __restrict__ h, const float* __restrict__ pw,
                            float* __restrict__ out) {
  int idx = blockIdx.x * 256 + threadIdx.x;
  if (idx >= NN * 32) return;
  int n = idx / 32, c = idx % 32;
  float acc = 0.0f;
  #pragma unroll 8
  for (int u = 0; u < 32; u++) acc += h[n*80 + u] * pw[u*32 + c];
  out[idx] = acc * 0.17677669529663687f;
}

extern "C" void kernel_launch(void* const* d_in, const int* in_sizes, int n_in,
                              void* d_out, int out_size, void* d_ws, size_t ws_size,
                              hipStream_t stream) {
  const float* x       = (const float*)d_in[0];
  const float* pos     = (const float*)d_in[1];
  const int*   ei      = (const int*)  d_in[2];
  const float* embed_w = (const float*)d_in[3];
  const float* proj_w  = (const float*)d_in[4];
  const float* lin_ws  = (const float*)d_in[5];
  const float* lin_wv  = (const float*)d_in[6];
  const float* sc_ws   = (const float*)d_in[7];
  const float* sc_wv   = (const float*)d_in[8];
  const float* mlp_w1  = (const float*)d_in[9];
  const float* mlp_b1  = (const float*)d_in[10];
  const float* mlp_w2  = (const float*)d_in[11];
  const float* mlp_b2  = (const float*)d_in[12];
  const float* mlp_w3  = (const float*)d_in[13];
  const float* mlp_b3  = (const float*)d_in[14];
  float* out = (float*)d_out;

  float* ws    = (float*)d_ws;
  float* egeo  = ws;                       // NE*20
  float* h     = egeo  + (size_t)NE*20;    // NN*80
  float* hx    = h     + (size_t)NN*80;    // NN*80
  float* xself = hx    + (size_t)NN*80;    // NN*80
  float* fbuf  = xself + (size_t)NN*80;    // NE*64
  float* agg   = fbuf  + (size_t)NE*64;    // NN*96

  geom_kernel<<<(NE + 255)/256, 256, 0, stream>>>(pos, ei, egeo);
  embed_kernel<<<(NN*80 + 255)/256, 256, 0, stream>>>(x, embed_w, h);
  for (int l = 0; l < 4; l++) {
    radial_kernel<<<NE/4, 256, 0, stream>>>(egeo, mlp_w1, mlp_b1, mlp_w2, mlp_b2, fbuf, l);
    node_lin_kernel<<<(NN*160 + 255)/256, 256, 0, stream>>>(h, lin_ws, lin_wv, sc_ws, sc_wv, hx, xself, l);
    hipMemsetAsync(agg, 0, (size_t)NN*96*sizeof(float), stream);
    edge_msg_kernel<<<NE/32, 256, 0, stream>>>(ei, egeo, fbuf, hx, mlp_w3, mlp_b3, agg, l);
    node_update_kernel<<<(NN*80 + 255)/256, 256, 0, stream>>>(agg, xself, h);
  }
  proj_kernel<<<(NN*32 + 255)/256, 256, 0, stream>>>(h, proj_w, out);
}

// Round 3
// 1141.066 us; speedup vs baseline: 3.1839x; 3.1839x over previous
//
#include <hip/hip_runtime.h>
#include <math.h>

#define NN 2048
#define NE 49152
#define WNUM 3328

typedef __attribute__((ext_vector_type(8))) short short8;
typedef __attribute__((ext_vector_type(4))) float f32x4;

__device__ __forceinline__ float silu_f(float x){ return x / (1.0f + expf(-x)); }
__device__ __forceinline__ float sigm_f(float x){ return 1.0f / (1.0f + expf(-x)); }

__device__ __forceinline__ unsigned short bf_hi(float x){
  unsigned int u = __float_as_uint(x);
  return (unsigned short)((u + 0x7FFFu + ((u >> 16) & 1u)) >> 16);
}
__device__ __forceinline__ float bf_to_f(unsigned short h){
  return __uint_as_float(((unsigned int)h) << 16);
}

// ---------------- edge geometry: y1(3), Ay(9), rbf(8) -> egeo stride 20; + dst histogram ----
__global__ void geom_kernel(const float* __restrict__ pos, const int* __restrict__ ei,
                            float* __restrict__ egeo, int* __restrict__ cnt) {
  int e = blockIdx.x * 256 + threadIdx.x;
  if (e >= NE) return;
  int s = ei[e], d = ei[NE + e];
  atomicAdd(&cnt[d], 1);
  float rx = pos[d*3+0] - pos[s*3+0];
  float ry = pos[d*3+1] - pos[s*3+1];
  float rz = pos[d*3+2] - pos[s*3+2];
  float r = sqrtf(rx*rx + ry*ry + rz*rz);
  r = fmaxf(r, 1e-6f);
  float x = rx / r, y = ry / r, z = rz / r;
  const float s3 = 1.7320508075688772f;
  const float c15 = 3.872983346207417f;
  float y2_0 = c15 * x * y;
  float y2_1 = c15 * y * z;
  float y2_2 = 1.118033988749895f * (3.0f*z*z - 1.0f);
  float y2_3 = c15 * x * z;
  float y2_4 = 1.9364916731037085f * (x*x - y*y);
  const float q2 = 0.7071067811865476f;
  const float q6 = 0.4082482904638631f;
  float* g = egeo + (size_t)e * 20;
  g[0] = s3 * x; g[1] = s3 * y; g[2] = s3 * z;
  g[3+0] = -q6*y2_2 + q2*y2_4;
  g[3+1] =  q2*y2_0;
  g[3+2] =  q2*y2_3;
  g[3+3] =  q2*y2_0;
  g[3+4] = -q6*y2_2 - q2*y2_4;
  g[3+5] =  q2*y2_1;
  g[3+6] =  q2*y2_3;
  g[3+7] =  q2*y2_1;
  g[3+8] =  2.0f*q6*y2_2;
  float u = r / 6.0f;
  float fc = 0.0f;
  if (u < 1.0f) {
    float u2=u*u, u3=u2*u, u6=u3*u3, u7=u6*u, u8=u7*u;
    fc = 1.0f - 28.0f*u6 + 48.0f*u7 - 21.0f*u8;
  }
  const float pref = 0.5773502691896258f;
  const float pi6 = 0.5235987755982988f;
  #pragma unroll
  for (int n = 1; n <= 8; n++) {
    g[12 + n - 1] = pref * sinf((float)n * pi6 * r) / r * fc;
  }
}

// ---------------- CSR scan: cnt[2048] -> offs[2049], cursor copy ----------------
__global__ void scan_kernel(const int* __restrict__ cnt, int* __restrict__ offs,
                            int* __restrict__ cursor) {
  __shared__ int part[256];
  int t = threadIdx.x;
  int local[8];
  int s = 0;
  #pragma unroll
  for (int j = 0; j < 8; j++) { local[j] = s; s += cnt[t*8 + j]; }
  part[t] = s;
  __syncthreads();
  for (int off = 1; off < 256; off <<= 1) {
    int v = part[t];
    int add = (t >= off) ? part[t - off] : 0;
    __syncthreads();
    part[t] = v + add;
    __syncthreads();
  }
  int excl = (t == 0) ? 0 : part[t-1];
  #pragma unroll
  for (int j = 0; j < 8; j++) {
    int o = excl + local[j];
    offs[t*8 + j] = o;
    cursor[t*8 + j] = o;
  }
  if (t == 255) offs[2048] = part[255];
}

__global__ void scatter_kernel(const int* __restrict__ ei, int* __restrict__ cursor,
                               int* __restrict__ eidx) {
  int e = blockIdx.x * 256 + threadIdx.x;
  if (e >= NE) return;
  int d = ei[NE + e];
  int p = atomicAdd(&cursor[d], 1);
  eidx[p] = e;
}

// ---------------- embed ----------------
__global__ void embed_kernel(const float* __restrict__ x, const float* __restrict__ ew,
                             float* __restrict__ h) {
  int idx = blockIdx.x * 256 + threadIdx.x;
  if (idx >= NN * 80) return;
  int n = idx / 80, c = idx % 80;
  float v = 0.0f;
  if (c < 32) {
    #pragma unroll
    for (int j = 0; j < 16; j++) v += x[n*16 + j] * ew[j*32 + c];
    v *= 0.25f;
  }
  h[idx] = v;
}

// ---------------- radial MLP -> f split to bf16 hi/lo ----------------
__global__ void radial_kernel(const float* __restrict__ egeo,
                              const float* __restrict__ w1, const float* __restrict__ b1,
                              const float* __restrict__ w2, const float* __restrict__ b2,
                              unsigned short* __restrict__ f_hi, unsigned short* __restrict__ f_lo,
                              int l) {
  __shared__ float h1[4][64];
  int ty = threadIdx.x >> 6, dk = threadIdx.x & 63;
  int e = blockIdx.x * 4 + ty;
  const float* w1l = w1 + (size_t)l * 8 * 64;
  const float* w2l = w2 + (size_t)l * 64 * 64;
  float acc = b1[l*64 + dk];
  const float* rb = egeo + (size_t)e * 20 + 12;
  #pragma unroll
  for (int j = 0; j < 8; j++) acc += rb[j] * w1l[j*64 + dk];
  h1[ty][dk] = silu_f(acc);
  __syncthreads();
  float acc2 = b2[l*64 + dk];
  #pragma unroll 8
  for (int j = 0; j < 64; j++) acc2 += h1[ty][j] * w2l[j*64 + dk];
  float val = silu_f(acc2);
  unsigned short hb = bf_hi(val);
  unsigned short lb = bf_hi(val - bf_to_f(hb));
  f_hi[(size_t)e*64 + dk] = hb;
  f_lo[(size_t)e*64 + dk] = lb;
}

// ---------------- node linears ----------------
__global__ void node_lin_kernel(const float* __restrict__ h,
                                const float* __restrict__ lws, const float* __restrict__ lwv,
                                const float* __restrict__ sws, const float* __restrict__ swv,
                                float* __restrict__ hx, float* __restrict__ xself, int l) {
  int idx = blockIdx.x * 256 + threadIdx.x;
  if (idx >= NN * 160) return;
  int which = (idx >= NN * 80) ? 1 : 0;
  int r = which ? idx - NN*80 : idx;
  int n = r / 80, c = r % 80;
  const float* Ws = (which ? sws : lws) + (size_t)l * 1024;
  const float* Wv = (which ? swv : lwv) + (size_t)l * 256;
  float v = 0.0f;
  if (c < 32) {
    #pragma unroll 8
    for (int u = 0; u < 32; u++) v += h[n*80 + u] * Ws[u*32 + c];
    v *= 0.17677669529663687f;
  } else {
    int oc = c - 32, wch = oc / 3, i = oc % 3;
    #pragma unroll
    for (int u = 0; u < 16; u++) v += h[n*80 + 32 + u*3 + i] * Wv[u*16 + wch];
    v *= 0.25f;
  }
  (which ? xself : hx)[n*80 + c] = v;
}

// ---------------- fused MFMA weight-GEMM + tensor product -> msg ----------------
__launch_bounds__(256, 2)
__global__ void edge_msg_kernel(const int* __restrict__ ei, const float* __restrict__ egeo,
                                const unsigned short* __restrict__ f_hi,
                                const unsigned short* __restrict__ f_lo,
                                const float* __restrict__ hx,
                                const float* __restrict__ w3g, const float* __restrict__ b3g,
                                float* __restrict__ msg, int l) {
  __shared__ unsigned short Bhi[64][72];   // W3 tile transposed [n][k], bf16 hi
  __shared__ unsigned short Blo[64][72];   // bf16 lo
  __shared__ float b3t[64];
  __shared__ float sT[32][64];             // s[u][e]
  __shared__ float p2T[16][64];            // p2[u][e]
  __shared__ float vT[48][64];             // v[u*3+i][e]
  __shared__ float q5T[48][64];            // q5[u*3+i][e]

  const int t = threadIdx.x;
  const int e0 = blockIdx.x * 64;
  const float* w3l = w3g + (size_t)l * 64 * WNUM;
  const float* b3l = b3g + (size_t)l * WNUM;

  // ---- prologue: gather hx[src] into transposed LDS ----
  for (int idx = t; idx < 64*80; idx += 256) {
    int e = idx / 80, c = idx % 80;
    int src = ei[e0 + e];
    float val = hx[(size_t)src*80 + c];
    if (c < 32) sT[c][e] = val; else vT[c-32][e] = val;
  }
  __syncthreads();
  // p2
  for (int idx = t; idx < 64*16; idx += 256) {
    int u = idx >> 6, e = idx & 63;
    const float* g = &egeo[(size_t)(e0+e)*20];
    float a = vT[u*3][e]*g[0] + vT[u*3+1][e]*g[1] + vT[u*3+2][e]*g[2];
    p2T[u][e] = a * 0.5773502691896258f;
  }
  // q5
  for (int idx = t; idx < 64*48; idx += 256) {
    int o = idx >> 6, e = idx & 63;
    int u = o / 3, jj = o % 3;
    const float* Ay = &egeo[(size_t)(e0+e)*20 + 3];
    float a = vT[u*3][e]*Ay[jj] + vT[u*3+1][e]*Ay[3+jj] + vT[u*3+2][e]*Ay[6+jj];
    q5T[o][e] = a * 0.7745966692414834f;
  }

  const int wv = t >> 6, lane = t & 63, L = lane & 15, quad = lane >> 4;
  const int eA = e0 + wv*16 + L;          // A-operand row edge (global)
  const int eloc = wv*16 + quad*4;        // C-operand row-base edge (block-local)
  const int eq = e0 + eloc;               // C-operand row-base edge (global)

  // A fragments (registers, once per block)
  const short8* fh = (const short8*)(f_hi + (size_t)eA*64);
  const short8* fl = (const short8*)(f_lo + (size_t)eA*64);
  short8 Ah0 = fh[quad], Ah1 = fh[4 + quad];
  short8 Al0 = fl[quad], Al1 = fl[4 + quad];

  // per-lane y1 for the 4 owned edges
  f32x4 y1r0, y1r1, y1r2;
  #pragma unroll
  for (int r = 0; r < 4; r++) {
    const float* g = &egeo[(size_t)(eq + r)*20];
    y1r0[r] = g[0]; y1r1[r] = g[1]; y1r2[r] = g[2];
  }

  f32x4 ms0 = {0,0,0,0}, ms1 = {0,0,0,0}, ms2 = {0,0,0,0};
  f32x4 mv0 = {0,0,0,0}, mv1 = {0,0,0,0}, mv2 = {0,0,0,0};

  const int ccol = t & 63, kg = t >> 6;   // staging assignment
  float wreg[16];
  // preload tile 0
  {
    const float* src = w3l + (size_t)(kg*16)*WNUM + ccol;
    #pragma unroll
    for (int kk = 0; kk < 16; kk++) wreg[kk] = src[(size_t)kk*WNUM];
  }
  float bpre = (t < 64) ? b3l[t] : 0.0f;

  for (int tile = 0; tile < 52; ++tile) {
    const int n0 = tile * 64;
    __syncthreads();   // previous tile compute done
    // convert + store staged W3 tile
    #pragma unroll
    for (int g8 = 0; g8 < 2; ++g8) {
      short8 hv, lv;
      #pragma unroll
      for (int j = 0; j < 8; ++j) {
        float xw = wreg[g8*8 + j];
        unsigned short hb = bf_hi(xw);
        float rest = xw - bf_to_f(hb);
        unsigned short lb = bf_hi(rest);
        hv[j] = (short)hb; lv[j] = (short)lb;
      }
      *(short8*)&Bhi[ccol][kg*16 + g8*8] = hv;
      *(short8*)&Blo[ccol][kg*16 + g8*8] = lv;
    }
    if (t < 64) b3t[t] = bpre;
    // prefetch next tile into registers
    if (tile + 1 < 52) {
      const float* src = w3l + (size_t)(kg*16)*WNUM + (n0 + 64) + ccol;
      #pragma unroll
      for (int kk = 0; kk < 16; kk++) wreg[kk] = src[(size_t)kk*WNUM];
      if (t < 64) bpre = b3l[n0 + 64 + t];
    }
    __syncthreads();

    #pragma unroll
    for (int st = 0; st < 4; ++st) {
      const int nrow = st*16 + L;
      short8 Bh0 = *(const short8*)&Bhi[nrow][quad*8];
      short8 Bh1 = *(const short8*)&Bhi[nrow][32 + quad*8];
      short8 Bl0 = *(const short8*)&Blo[nrow][quad*8];
      short8 Bl1 = *(const short8*)&Blo[nrow][32 + quad*8];
      float bb = b3t[st*16 + L];
      f32x4 acc = {bb, bb, bb, bb};
      acc = __builtin_amdgcn_mfma_f32_16x16x32_bf16(Ah0, Bh0, acc, 0, 0, 0);
      acc = __builtin_amdgcn_mfma_f32_16x16x32_bf16(Ah1, Bh1, acc, 0, 0, 0);
      acc = __builtin_amdgcn_mfma_f32_16x16x32_bf16(Al0, Bh0, acc, 0, 0, 0);
      acc = __builtin_amdgcn_mfma_f32_16x16x32_bf16(Al1, Bh1, acc, 0, 0, 0);
      acc = __builtin_amdgcn_mfma_f32_16x16x32_bf16(Ah0, Bl0, acc, 0, 0, 0);
      acc = __builtin_amdgcn_mfma_f32_16x16x32_bf16(Ah1, Bl1, acc, 0, 0, 0);

      const int cb = n0 + st*16;   // absolute column base (uniform)
      if (cb < 1536) {
        int u = cb / 48, j = (cb % 48) >> 4;
        f32x4 fac = *(const f32x4*)&sT[u][eloc];
        if (j == 0) ms0 += fac*acc; else if (j == 1) ms1 += fac*acc; else ms2 += fac*acc;
      } else if (cb < 2304) {
        int u = (cb - 1536) / 48, j = ((cb - 1536) % 48) >> 4;
        f32x4 fac = *(const f32x4*)&p2T[u][eloc];
        if (j == 0) ms0 += fac*acc; else if (j == 1) ms1 += fac*acc; else ms2 += fac*acc;
      } else if (cb < 2816) {
        int u = (cb - 2304) >> 4;
        f32x4 fac = *(const f32x4*)&sT[u][eloc];
        mv0 += (fac * y1r0) * acc;
        mv1 += (fac * y1r1) * acc;
        mv2 += (fac * y1r2) * acc;
      } else if (cb < 3072) {
        int u = (cb - 2816) >> 4;
        mv0 += *(const f32x4*)&vT[u*3+0][eloc] * acc;
        mv1 += *(const f32x4*)&vT[u*3+1][eloc] * acc;
        mv2 += *(const f32x4*)&vT[u*3+2][eloc] * acc;
      } else {
        int u = (cb - 3072) >> 4;
        mv0 += *(const f32x4*)&q5T[u*3+0][eloc] * acc;
        mv1 += *(const f32x4*)&q5T[u*3+1][eloc] * acc;
        mv2 += *(const f32x4*)&q5T[u*3+2][eloc] * acc;
      }
    }
  }

  // epilogue: scaled write of msg
  const float S48 = 0.14433756729740645f;  // 1/sqrt(48)
  const float S64 = 0.125f;                // 1/sqrt(64)
  #pragma unroll
  for (int r = 0; r < 4; ++r) {
    float* mp = msg + (size_t)(eq + r)*96;
    mp[L]        = ms0[r] * S48;
    mp[16 + L]   = ms1[r] * S48;
    mp[32 + L]   = ms2[r] * S48;
    mp[48 + 3*L]     = mv0[r] * S64;
    mp[48 + 3*L + 1] = mv1[r] * S64;
    mp[48 + 3*L + 2] = mv2[r] * S64;
  }
}

// ---------------- CSR gather: agg[n][c] = sum msg over incoming edges ----------------
__global__ void agg_gather_kernel(const float* __restrict__ msg, const int* __restrict__ offs,
                                  const int* __restrict__ eidx, float* __restrict__ agg) {
  int idx = blockIdx.x * 256 + threadIdx.x;
  if (idx >= NN * 96) return;
  int n = idx / 96, c = idx % 96;
  int b = offs[n], e = offs[n+1];
  float acc = 0.0f;
  for (int j = b; j < e; ++j) acc += msg[(size_t)eidx[j]*96 + c];
  agg[idx] = acc * 0.20412414523193154f;   // 1/sqrt(24)
}

// ---------------- node update ----------------
__global__ void node_update_kernel(const float* __restrict__ agg, const float* __restrict__ xself,
                                   float* __restrict__ h) {
  int idx = blockIdx.x * 256 + threadIdx.x;
  if (idx >= NN * 80) return;
  int n = idx / 80, c = idx % 80;
  float a;
  if (c < 32) {
    a = silu_f(agg[(size_t)n*96 + c]);
  } else {
    int oc = c - 32, wch = oc / 3;
    float gg = sigm_f(agg[(size_t)n*96 + 32 + wch]);
    a = agg[(size_t)n*96 + 48 + oc] * gg;
  }
  h[idx] = h[idx] + xself[idx] + a;
}

// ---------------- final projection ----------------
__global__ void proj_kernel(const float* __restrict__ h, const float* __restrict__ pw,
                            float* __restrict__ out) {
  int idx = blockIdx.x * 256 + threadIdx.x;
  if (idx >= NN * 32) return;
  int n = idx / 32, c = idx % 32;
  float acc = 0.0f;
  #pragma unroll 8
  for (int u = 0; u < 32; u++) acc += h[n*80 + u] * pw[u*32 + c];
  out[idx] = acc * 0.17677669529663687f;
}

extern "C" void kernel_launch(void* const* d_in, const int* in_sizes, int n_in,
                              void* d_out, int out_size, void* d_ws, size_t ws_size,
                              hipStream_t stream) {
  const float* x       = (const float*)d_in[0];
  const float* pos     = (const float*)d_in[1];
  const int*   ei      = (const int*)  d_in[2];
  const float* embed_w = (const float*)d_in[3];
  const float* proj_w  = (const float*)d_in[4];
  const float* lin_ws  = (const float*)d_in[5];
  const float* lin_wv  = (const float*)d_in[6];
  const float* sc_ws   = (const float*)d_in[7];
  const float* sc_wv   = (const float*)d_in[8];
  const float* mlp_w1  = (const float*)d_in[9];
  const float* mlp_b1  = (const float*)d_in[10];
  const float* mlp_w2  = (const float*)d_in[11];
  const float* mlp_b2  = (const float*)d_in[12];
  const float* mlp_w3  = (const float*)d_in[13];
  const float* mlp_b3  = (const float*)d_in[14];
  float* out = (float*)d_out;

  float* ws    = (float*)d_ws;
  float* egeo  = ws;                          // NE*20
  float* h     = egeo  + (size_t)NE*20;       // NN*80
  float* hx    = h     + (size_t)NN*80;       // NN*80
  float* xself = hx    + (size_t)NN*80;       // NN*80
  float* agg   = xself + (size_t)NN*80;       // NN*96
  float* msg   = agg   + (size_t)NN*96;       // NE*96
  unsigned short* f_hi = (unsigned short*)(msg + (size_t)NE*96);  // NE*64 u16
  unsigned short* f_lo = f_hi + (size_t)NE*64;                    // NE*64 u16
  int* cnt    = (int*)(f_lo + (size_t)NE*64); // NN
  int* offs   = cnt + NN;                     // NN+1
  int* cursor = offs + NN + 1;                // NN
  int* eidxb  = cursor + NN;                  // NE

  hipMemsetAsync(cnt, 0, NN*sizeof(int), stream);
  geom_kernel<<<(NE + 255)/256, 256, 0, stream>>>(pos, ei, egeo, cnt);
  scan_kernel<<<1, 256, 0, stream>>>(cnt, offs, cursor);
  scatter_kernel<<<NE/256, 256, 0, stream>>>(ei, cursor, eidxb);
  embed_kernel<<<(NN*80 + 255)/256, 256, 0, stream>>>(x, embed_w, h);

  for (int l = 0; l < 4; l++) {
    radial_kernel<<<NE/4, 256, 0, stream>>>(egeo, mlp_w1, mlp_b1, mlp_w2, mlp_b2, f_hi, f_lo, l);
    node_lin_kernel<<<(NN*160 + 255)/256, 256, 0, stream>>>(h, lin_ws, lin_wv, sc_ws, sc_wv, hx, xself, l);
    edge_msg_kernel<<<NE/64, 256, 0, stream>>>(ei, egeo, f_hi, f_lo, hx, mlp_w3, mlp_b3, msg, l);
    agg_gather_kernel<<<(NN*96 + 255)/256, 256, 0, stream>>>(msg, offs, eidxb, agg);
    node_update_kernel<<<(NN*80 + 255)/256, 256, 0, stream>>>(agg, xself, h);
  }
  proj_kernel<<<(NN*32 + 255)/256, 256, 0, stream>>>(h, proj_w, out);
}

// Round 4
// 789.270 us; speedup vs baseline: 4.6030x; 1.4457x over previous
//
#include <hip/hip_runtime.h>
#include <math.h>

#define NN 2048
#define NE 49152
#define WNUM 3328

typedef __attribute__((ext_vector_type(8))) short short8;
typedef __attribute__((ext_vector_type(4))) float f32x4;

__device__ __forceinline__ float silu_f(float x){ return x / (1.0f + expf(-x)); }
__device__ __forceinline__ float sigm_f(float x){ return 1.0f / (1.0f + expf(-x)); }

__device__ __forceinline__ unsigned short bf_hi(float x){
  unsigned int u = __float_as_uint(x);
  return (unsigned short)((u + 0x7FFFu + ((u >> 16) & 1u)) >> 16);
}
__device__ __forceinline__ float bf_to_f(unsigned short h){
  return __uint_as_float(((unsigned int)h) << 16);
}

// ---------------- edge geometry: y1(3), Ay(9), rbf(8) -> egeo stride 20; + dst histogram ----
__global__ void geom_kernel(const float* __restrict__ pos, const int* __restrict__ ei,
                            float* __restrict__ egeo, int* __restrict__ cnt) {
  int e = blockIdx.x * 256 + threadIdx.x;
  if (e >= NE) return;
  int s = ei[e], d = ei[NE + e];
  atomicAdd(&cnt[d], 1);
  float rx = pos[d*3+0] - pos[s*3+0];
  float ry = pos[d*3+1] - pos[s*3+1];
  float rz = pos[d*3+2] - pos[s*3+2];
  float r = sqrtf(rx*rx + ry*ry + rz*rz);
  r = fmaxf(r, 1e-6f);
  float x = rx / r, y = ry / r, z = rz / r;
  const float s3 = 1.7320508075688772f;
  const float c15 = 3.872983346207417f;
  float y2_0 = c15 * x * y;
  float y2_1 = c15 * y * z;
  float y2_2 = 1.118033988749895f * (3.0f*z*z - 1.0f);
  float y2_3 = c15 * x * z;
  float y2_4 = 1.9364916731037085f * (x*x - y*y);
  const float q2 = 0.7071067811865476f;
  const float q6 = 0.4082482904638631f;
  float* g = egeo + (size_t)e * 20;
  g[0] = s3 * x; g[1] = s3 * y; g[2] = s3 * z;
  g[3+0] = -q6*y2_2 + q2*y2_4;
  g[3+1] =  q2*y2_0;
  g[3+2] =  q2*y2_3;
  g[3+3] =  q2*y2_0;
  g[3+4] = -q6*y2_2 - q2*y2_4;
  g[3+5] =  q2*y2_1;
  g[3+6] =  q2*y2_3;
  g[3+7] =  q2*y2_1;
  g[3+8] =  2.0f*q6*y2_2;
  float u = r / 6.0f;
  float fc = 0.0f;
  if (u < 1.0f) {
    float u2=u*u, u3=u2*u, u6=u3*u3, u7=u6*u, u8=u7*u;
    fc = 1.0f - 28.0f*u6 + 48.0f*u7 - 21.0f*u8;
  }
  const float pref = 0.5773502691896258f;
  const float pi6 = 0.5235987755982988f;
  #pragma unroll
  for (int n = 1; n <= 8; n++) {
    g[12 + n - 1] = pref * sinf((float)n * pi6 * r) / r * fc;
  }
}

// ---------------- CSR scan ----------------
__global__ void scan_kernel(const int* __restrict__ cnt, int* __restrict__ offs,
                            int* __restrict__ cursor) {
  __shared__ int part[256];
  int t = threadIdx.x;
  int local[8];
  int s = 0;
  #pragma unroll
  for (int j = 0; j < 8; j++) { local[j] = s; s += cnt[t*8 + j]; }
  part[t] = s;
  __syncthreads();
  for (int off = 1; off < 256; off <<= 1) {
    int v = part[t];
    int add = (t >= off) ? part[t - off] : 0;
    __syncthreads();
    part[t] = v + add;
    __syncthreads();
  }
  int excl = (t == 0) ? 0 : part[t-1];
  #pragma unroll
  for (int j = 0; j < 8; j++) {
    int o = excl + local[j];
    offs[t*8 + j] = o;
    cursor[t*8 + j] = o;
  }
  if (t == 255) offs[2048] = part[255];
}

__global__ void scatter_kernel(const int* __restrict__ ei, int* __restrict__ cursor,
                               int* __restrict__ eidx) {
  int e = blockIdx.x * 256 + threadIdx.x;
  if (e >= NE) return;
  int d = ei[NE + e];
  int p = atomicAdd(&cursor[d], 1);
  eidx[p] = e;
}

// ---------------- W3 -> bf16 hi/lo, MFMA-B-fragment-ordered ----------------
// Layout: w3bf[((l*208 + idx)*4 + plane)*64*8 + lane*8 + j]  (ushort)
//   idx = n>>4 (n = output col), lane = quad*16 + (n&15)
//   plane 0: hi of B[k=quad*8+j][n];  plane 1: hi of B[k=32+quad*8+j][n]
//   plane 2: lo of same as p0;        plane 3: lo of same as p1
__global__ void conv_w3_kernel(const float* __restrict__ w3g, unsigned short* __restrict__ w3bf) {
  int tid = blockIdx.x * 256 + threadIdx.x;
  if (tid >= 16 * WNUM) return;
  int n = tid % WNUM;
  int lq = tid / WNUM;           // l*4 + quad
  int quad = lq & 3, l = lq >> 2;
  const float* src = w3g + (size_t)l * 64 * WNUM + n;
  int idx = n >> 4, L = n & 15;
  unsigned short* dst = w3bf + (((size_t)l * 208 + idx) * 4) * 512 + (quad*16 + L) * 8;
  short8 h0, h1, l0v, l1v;
  #pragma unroll
  for (int j = 0; j < 8; j++) {
    float a = src[(size_t)(quad*8 + j) * WNUM];
    float b = src[(size_t)(32 + quad*8 + j) * WNUM];
    unsigned short ha = bf_hi(a);
    unsigned short hb = bf_hi(b);
    h0[j] = (short)ha;  l0v[j] = (short)bf_hi(a - bf_to_f(ha));
    h1[j] = (short)hb;  l1v[j] = (short)bf_hi(b - bf_to_f(hb));
  }
  *(short8*)(dst)        = h0;
  *(short8*)(dst + 512)  = h1;
  *(short8*)(dst + 1024) = l0v;
  *(short8*)(dst + 1536) = l1v;
}

// ---------------- embed ----------------
__global__ void embed_kernel(const float* __restrict__ x, const float* __restrict__ ew,
                             float* __restrict__ h) {
  int idx = blockIdx.x * 256 + threadIdx.x;
  if (idx >= NN * 80) return;
  int n = idx / 80, c = idx % 80;
  float v = 0.0f;
  if (c < 32) {
    #pragma unroll
    for (int j = 0; j < 16; j++) v += x[n*16 + j] * ew[j*32 + c];
    v *= 0.25f;
  }
  h[idx] = v;
}

// ---------------- radial MLP -> f split to bf16 hi/lo ----------------
__global__ void radial_kernel(const float* __restrict__ egeo,
                              const float* __restrict__ w1, const float* __restrict__ b1,
                              const float* __restrict__ w2, const float* __restrict__ b2,
                              unsigned short* __restrict__ f_hi, unsigned short* __restrict__ f_lo,
                              int l) {
  __shared__ float h1[4][64];
  int ty = threadIdx.x >> 6, dk = threadIdx.x & 63;
  int e = blockIdx.x * 4 + ty;
  const float* w1l = w1 + (size_t)l * 8 * 64;
  const float* w2l = w2 + (size_t)l * 64 * 64;
  float acc = b1[l*64 + dk];
  const float* rb = egeo + (size_t)e * 20 + 12;
  #pragma unroll
  for (int j = 0; j < 8; j++) acc += rb[j] * w1l[j*64 + dk];
  h1[ty][dk] = silu_f(acc);
  __syncthreads();
  float acc2 = b2[l*64 + dk];
  #pragma unroll 8
  for (int j = 0; j < 64; j++) acc2 += h1[ty][j] * w2l[j*64 + dk];
  float val = silu_f(acc2);
  unsigned short hb = bf_hi(val);
  unsigned short lb = bf_hi(val - bf_to_f(hb));
  f_hi[(size_t)e*64 + dk] = hb;
  f_lo[(size_t)e*64 + dk] = lb;
}

// ---------------- node linears ----------------
__global__ void node_lin_kernel(const float* __restrict__ h,
                                const float* __restrict__ lws, const float* __restrict__ lwv,
                                const float* __restrict__ sws, const float* __restrict__ swv,
                                float* __restrict__ hx, float* __restrict__ xself, int l) {
  int idx = blockIdx.x * 256 + threadIdx.x;
  if (idx >= NN * 160) return;
  int which = (idx >= NN * 80) ? 1 : 0;
  int r = which ? idx - NN*80 : idx;
  int n = r / 80, c = r % 80;
  const float* Ws = (which ? sws : lws) + (size_t)l * 1024;
  const float* Wv = (which ? swv : lwv) + (size_t)l * 256;
  float v = 0.0f;
  if (c < 32) {
    #pragma unroll 8
    for (int u = 0; u < 32; u++) v += h[n*80 + u] * Ws[u*32 + c];
    v *= 0.17677669529663687f;
  } else {
    int oc = c - 32, wch = oc / 3, i = oc % 3;
    #pragma unroll
    for (int u = 0; u < 16; u++) v += h[n*80 + 32 + u*3 + i] * Wv[u*16 + wch];
    v *= 0.25f;
  }
  (which ? xself : hx)[n*80 + c] = v;
}

// ---------------- fused MFMA weight-GEMM + tensor product -> msg ----------------
// B-frags stream straight from the fragment-ordered global buffer: no LDS for B,
// no barriers in the K-loop, 1-step register pipeline.
__launch_bounds__(256, 4)
__global__ void edge_msg_kernel(const int* __restrict__ ei, const float* __restrict__ egeo,
                                const unsigned short* __restrict__ f_hi,
                                const unsigned short* __restrict__ f_lo,
                                const float* __restrict__ hx,
                                const unsigned short* __restrict__ w3bf,
                                const float* __restrict__ b3g,
                                float* __restrict__ msg, int l) {
  __shared__ float sT[32][64];             // s[u][e]
  __shared__ float p2T[16][64];            // p2[u][e]
  __shared__ float vT[48][64];             // v[u*3+i][e]
  __shared__ float q5T[48][64];            // q5[u*3+i][e]

  const int t = threadIdx.x;
  const int e0 = blockIdx.x * 64;
  const float* b3l = b3g + (size_t)l * WNUM;

  // ---- prologue: gather hx[src] into transposed LDS ----
  for (int idx = t; idx < 64*80; idx += 256) {
    int e = idx / 80, c = idx % 80;
    int src = ei[e0 + e];
    float val = hx[(size_t)src*80 + c];
    if (c < 32) sT[c][e] = val; else vT[c-32][e] = val;
  }
  __syncthreads();
  for (int idx = t; idx < 64*16; idx += 256) {
    int u = idx >> 6, e = idx & 63;
    const float* g = &egeo[(size_t)(e0+e)*20];
    float a = vT[u*3][e]*g[0] + vT[u*3+1][e]*g[1] + vT[u*3+2][e]*g[2];
    p2T[u][e] = a * 0.5773502691896258f;
  }
  for (int idx = t; idx < 64*48; idx += 256) {
    int o = idx >> 6, e = idx & 63;
    int u = o / 3, jj = o % 3;
    const float* Ay = &egeo[(size_t)(e0+e)*20 + 3];
    float a = vT[u*3][e]*Ay[jj] + vT[u*3+1][e]*Ay[3+jj] + vT[u*3+2][e]*Ay[6+jj];
    q5T[o][e] = a * 0.7745966692414834f;
  }

  const int wv = t >> 6, lane = t & 63, L = lane & 15, quad = lane >> 4;
  const int eA = e0 + wv*16 + L;          // A-operand row edge (global)
  const int eloc = wv*16 + quad*4;        // C-operand row-base edge (block-local)
  const int eq = e0 + eloc;               // C-operand row-base edge (global)

  // A fragments (registers, once per block)
  const short8* fh = (const short8*)(f_hi + (size_t)eA*64);
  const short8* fl = (const short8*)(f_lo + (size_t)eA*64);
  short8 Ah0 = fh[quad], Ah1 = fh[4 + quad];
  short8 Al0 = fl[quad], Al1 = fl[4 + quad];

  // per-lane y1 for the 4 owned edges
  f32x4 y1r0, y1r1, y1r2;
  #pragma unroll
  for (int r = 0; r < 4; r++) {
    const float* g = &egeo[(size_t)(eq + r)*20];
    y1r0[r] = g[0]; y1r1[r] = g[1]; y1r2[r] = g[2];
  }
  __syncthreads();   // factor LDS ready

  f32x4 ms0 = {0,0,0,0}, ms1 = {0,0,0,0}, ms2 = {0,0,0,0};
  f32x4 mv0 = {0,0,0,0}, mv1 = {0,0,0,0}, mv2 = {0,0,0,0};

  const unsigned short* wb = w3bf + (size_t)l * 208 * 2048 + lane * 8;
  // pipeline stage 0
  short8 nB0 = *(const short8*)(wb);
  short8 nB1 = *(const short8*)(wb + 512);
  short8 nB2 = *(const short8*)(wb + 1024);
  short8 nB3 = *(const short8*)(wb + 1536);
  float nbias = b3l[L];

  for (int idx = 0; idx < 208; ++idx) {
    short8 B0 = nB0, B1 = nB1, B2 = nB2, B3 = nB3;
    float bb = nbias;
    if (idx + 1 < 208) {
      const unsigned short* wn = wb + (size_t)(idx + 1) * 2048;
      nB0 = *(const short8*)(wn);
      nB1 = *(const short8*)(wn + 512);
      nB2 = *(const short8*)(wn + 1024);
      nB3 = *(const short8*)(wn + 1536);
      nbias = b3l[(idx + 1) * 16 + L];
    }
    f32x4 acc = {bb, bb, bb, bb};
    acc = __builtin_amdgcn_mfma_f32_16x16x32_bf16(Ah0, B0, acc, 0, 0, 0);
    acc = __builtin_amdgcn_mfma_f32_16x16x32_bf16(Ah1, B1, acc, 0, 0, 0);
    acc = __builtin_amdgcn_mfma_f32_16x16x32_bf16(Al0, B0, acc, 0, 0, 0);
    acc = __builtin_amdgcn_mfma_f32_16x16x32_bf16(Al1, B1, acc, 0, 0, 0);
    acc = __builtin_amdgcn_mfma_f32_16x16x32_bf16(Ah0, B2, acc, 0, 0, 0);
    acc = __builtin_amdgcn_mfma_f32_16x16x32_bf16(Ah1, B3, acc, 0, 0, 0);

    const int cb = idx << 4;     // absolute column base (uniform)
    if (cb < 1536) {
      int u = cb / 48, j = (cb % 48) >> 4;
      f32x4 fac = *(const f32x4*)&sT[u][eloc];
      if (j == 0) ms0 += fac*acc; else if (j == 1) ms1 += fac*acc; else ms2 += fac*acc;
    } else if (cb < 2304) {
      int u = (cb - 1536) / 48, j = ((cb - 1536) % 48) >> 4;
      f32x4 fac = *(const f32x4*)&p2T[u][eloc];
      if (j == 0) ms0 += fac*acc; else if (j == 1) ms1 += fac*acc; else ms2 += fac*acc;
    } else if (cb < 2816) {
      int u = (cb - 2304) >> 4;
      f32x4 fac = *(const f32x4*)&sT[u][eloc];
      mv0 += (fac * y1r0) * acc;
      mv1 += (fac * y1r1) * acc;
      mv2 += (fac * y1r2) * acc;
    } else if (cb < 3072) {
      int u = (cb - 2816) >> 4;
      mv0 += *(const f32x4*)&vT[u*3+0][eloc] * acc;
      mv1 += *(const f32x4*)&vT[u*3+1][eloc] * acc;
      mv2 += *(const f32x4*)&vT[u*3+2][eloc] * acc;
    } else {
      int u = (cb - 3072) >> 4;
      mv0 += *(const f32x4*)&q5T[u*3+0][eloc] * acc;
      mv1 += *(const f32x4*)&q5T[u*3+1][eloc] * acc;
      mv2 += *(const f32x4*)&q5T[u*3+2][eloc] * acc;
    }
  }

  // epilogue: scaled write of msg
  const float S48 = 0.14433756729740645f;  // 1/sqrt(48)
  const float S64 = 0.125f;                // 1/sqrt(64)
  #pragma unroll
  for (int r = 0; r < 4; ++r) {
    float* mp = msg + (size_t)(eq + r)*96;
    mp[L]        = ms0[r] * S48;
    mp[16 + L]   = ms1[r] * S48;
    mp[32 + L]   = ms2[r] * S48;
    mp[48 + 3*L]     = mv0[r] * S64;
    mp[48 + 3*L + 1] = mv1[r] * S64;
    mp[48 + 3*L + 2] = mv2[r] * S64;
  }
}

// ---------------- CSR gather ----------------
__global__ void agg_gather_kernel(const float* __restrict__ msg, const int* __restrict__ offs,
                                  const int* __restrict__ eidx, float* __restrict__ agg) {
  int idx = blockIdx.x * 256 + threadIdx.x;
  if (idx >= NN * 96) return;
  int n = idx / 96, c = idx % 96;
  int b = offs[n], e = offs[n+1];
  float acc = 0.0f;
  for (int j = b; j < e; ++j) acc += msg[(size_t)eidx[j]*96 + c];
  agg[idx] = acc * 0.20412414523193154f;   // 1/sqrt(24)
}

// ---------------- node update ----------------
__global__ void node_update_kernel(const float* __restrict__ agg, const float* __restrict__ xself,
                                   float* __restrict__ h) {
  int idx = blockIdx.x * 256 + threadIdx.x;
  if (idx >= NN * 80) return;
  int n = idx / 80, c = idx % 80;
  float a;
  if (c < 32) {
    a = silu_f(agg[(size_t)n*96 + c]);
  } else {
    int oc = c - 32, wch = oc / 3;
    float gg = sigm_f(agg[(size_t)n*96 + 32 + wch]);
    a = agg[(size_t)n*96 + 48 + oc] * gg;
  }
  h[idx] = h[idx] + xself[idx] + a;
}

// ---------------- final projection ----------------
__global__ void proj_kernel(const float* __restrict__ h, const float* __restrict__ pw,
                            float* __restrict__ out) {
  int idx = blockIdx.x * 256 + threadIdx.x;
  if (idx >= NN * 32) return;
  int n = idx / 32, c = idx % 32;
  float acc = 0.0f;
  #pragma unroll 8
  for (int u = 0; u < 32; u++) acc += h[n*80 + u] * pw[u*32 + c];
  out[idx] = acc * 0.17677669529663687f;
}

extern "C" void kernel_launch(void* const* d_in, const int* in_sizes, int n_in,
                              void* d_out, int out_size, void* d_ws, size_t ws_size,
                              hipStream_t stream) {
  const float* x       = (const float*)d_in[0];
  const float* pos     = (const float*)d_in[1];
  const int*   ei      = (const int*)  d_in[2];
  const float* embed_w = (const float*)d_in[3];
  const float* proj_w  = (const float*)d_in[4];
  const float* lin_ws  = (const float*)d_in[5];
  const float* lin_wv  = (const float*)d_in[6];
  const float* sc_ws   = (const float*)d_in[7];
  const float* sc_wv   = (const float*)d_in[8];
  const float* mlp_w1  = (const float*)d_in[9];
  const float* mlp_b1  = (const float*)d_in[10];
  const float* mlp_w2  = (const float*)d_in[11];
  const float* mlp_b2  = (const float*)d_in[12];
  const float* mlp_w3  = (const float*)d_in[13];
  const float* mlp_b3  = (const float*)d_in[14];
  float* out = (float*)d_out;

  float* ws    = (float*)d_ws;
  float* egeo  = ws;                          // NE*20
  float* h     = egeo  + (size_t)NE*20;       // NN*80
  float* hx    = h     + (size_t)NN*80;       // NN*80
  float* xself = hx    + (size_t)NN*80;       // NN*80
  float* agg   = xself + (size_t)NN*80;       // NN*96
  float* msg   = agg   + (size_t)NN*96;       // NE*96
  unsigned short* f_hi = (unsigned short*)(msg + (size_t)NE*96);  // NE*64 u16
  unsigned short* f_lo = f_hi + (size_t)NE*64;                    // NE*64 u16
  unsigned short* w3bf = f_lo + (size_t)NE*64;                    // 4*208*2048 u16
  int* cnt    = (int*)(w3bf + (size_t)4*208*2048); // NN
  int* offs   = cnt + NN;                     // NN+1
  int* cursor = offs + NN + 1;                // NN
  int* eidxb  = cursor + NN;                  // NE

  hipMemsetAsync(cnt, 0, NN*sizeof(int), stream);
  geom_kernel<<<(NE + 255)/256, 256, 0, stream>>>(pos, ei, egeo, cnt);
  scan_kernel<<<1, 256, 0, stream>>>(cnt, offs, cursor);
  scatter_kernel<<<NE/256, 256, 0, stream>>>(ei, cursor, eidxb);
  conv_w3_kernel<<<(16*WNUM + 255)/256, 256, 0, stream>>>(mlp_w3, w3bf);
  embed_kernel<<<(NN*80 + 255)/256, 256, 0, stream>>>(x, embed_w, h);

  for (int l = 0; l < 4; l++) {
    radial_kernel<<<NE/4, 256, 0, stream>>>(egeo, mlp_w1, mlp_b1, mlp_w2, mlp_b2, f_hi, f_lo, l);
    node_lin_kernel<<<(NN*160 + 255)/256, 256, 0, stream>>>(h, lin_ws, lin_wv, sc_ws, sc_wv, hx, xself, l);
    edge_msg_kernel<<<NE/64, 256, 0, stream>>>(ei, egeo, f_hi, f_lo, hx, w3bf, mlp_b3, msg, l);
    agg_gather_kernel<<<(NN*96 + 255)/256, 256, 0, stream>>>(msg, offs, eidxb, agg);
    node_update_kernel<<<(NN*80 + 255)/256, 256, 0, stream>>>(agg, xself, h);
  }
  proj_kernel<<<(NN*32 + 255)/256, 256, 0, stream>>>(h, proj_w, out);
}

// Round 5
// 689.380 us; speedup vs baseline: 5.2700x; 1.1449x over previous
//
#include <hip/hip_runtime.h>
#include <math.h>

#define NN 2048
#define NE 49152
#define WNUM 3328

typedef __attribute__((ext_vector_type(8))) _Float16 half8;
typedef __attribute__((ext_vector_type(4))) float f32x4;

__device__ __forceinline__ float silu_f(float x){ return x / (1.0f + expf(-x)); }
__device__ __forceinline__ float sigm_f(float x){ return 1.0f / (1.0f + expf(-x)); }

// ---------------- edge geometry: y1(3), Ay(9), rbf(8) -> egeo stride 20; + dst histogram ----
__global__ void geom_kernel(const float* __restrict__ pos, const int* __restrict__ ei,
                            float* __restrict__ egeo, int* __restrict__ cnt) {
  int e = blockIdx.x * 256 + threadIdx.x;
  if (e >= NE) return;
  int s = ei[e], d = ei[NE + e];
  atomicAdd(&cnt[d], 1);
  float rx = pos[d*3+0] - pos[s*3+0];
  float ry = pos[d*3+1] - pos[s*3+1];
  float rz = pos[d*3+2] - pos[s*3+2];
  float r = sqrtf(rx*rx + ry*ry + rz*rz);
  r = fmaxf(r, 1e-6f);
  float x = rx / r, y = ry / r, z = rz / r;
  const float s3 = 1.7320508075688772f;
  const float c15 = 3.872983346207417f;
  float y2_0 = c15 * x * y;
  float y2_1 = c15 * y * z;
  float y2_2 = 1.118033988749895f * (3.0f*z*z - 1.0f);
  float y2_3 = c15 * x * z;
  float y2_4 = 1.9364916731037085f * (x*x - y*y);
  const float q2 = 0.7071067811865476f;
  const float q6 = 0.4082482904638631f;
  float* g = egeo + (size_t)e * 20;
  g[0] = s3 * x; g[1] = s3 * y; g[2] = s3 * z;
  g[3+0] = -q6*y2_2 + q2*y2_4;
  g[3+1] =  q2*y2_0;
  g[3+2] =  q2*y2_3;
  g[3+3] =  q2*y2_0;
  g[3+4] = -q6*y2_2 - q2*y2_4;
  g[3+5] =  q2*y2_1;
  g[3+6] =  q2*y2_3;
  g[3+7] =  q2*y2_1;
  g[3+8] =  2.0f*q6*y2_2;
  float u = r / 6.0f;
  float fc = 0.0f;
  if (u < 1.0f) {
    float u2=u*u, u3=u2*u, u6=u3*u3, u7=u6*u, u8=u7*u;
    fc = 1.0f - 28.0f*u6 + 48.0f*u7 - 21.0f*u8;
  }
  const float pref = 0.5773502691896258f;
  const float pi6 = 0.5235987755982988f;
  #pragma unroll
  for (int n = 1; n <= 8; n++) {
    g[12 + n - 1] = pref * sinf((float)n * pi6 * r) / r * fc;
  }
}

// ---------------- CSR scan ----------------
__global__ void scan_kernel(const int* __restrict__ cnt, int* __restrict__ offs,
                            int* __restrict__ cursor) {
  __shared__ int part[256];
  int t = threadIdx.x;
  int local[8];
  int s = 0;
  #pragma unroll
  for (int j = 0; j < 8; j++) { local[j] = s; s += cnt[t*8 + j]; }
  part[t] = s;
  __syncthreads();
  for (int off = 1; off < 256; off <<= 1) {
    int v = part[t];
    int add = (t >= off) ? part[t - off] : 0;
    __syncthreads();
    part[t] = v + add;
    __syncthreads();
  }
  int excl = (t == 0) ? 0 : part[t-1];
  #pragma unroll
  for (int j = 0; j < 8; j++) {
    int o = excl + local[j];
    offs[t*8 + j] = o;
    cursor[t*8 + j] = o;
  }
  if (t == 255) offs[2048] = part[255];
}

__global__ void scatter_kernel(const int* __restrict__ ei, int* __restrict__ cursor,
                               int* __restrict__ eidx) {
  int e = blockIdx.x * 256 + threadIdx.x;
  if (e >= NE) return;
  int d = ei[NE + e];
  int p = atomicAdd(&cursor[d], 1);
  eidx[p] = e;
}

// ---------------- W3 -> f16, MFMA-B-fragment-ordered ----------------
// w3h[((l*208 + idx)*2 + plane)*512 + (quad*16+L)*8 + j]
//   plane 0: B[k=quad*8+j][n];  plane 1: B[k=32+quad*8+j][n];  n = idx*16+L
__global__ void conv_w3_kernel(const float* __restrict__ w3g, _Float16* __restrict__ w3h) {
  int tid = blockIdx.x * 256 + threadIdx.x;
  if (tid >= 16 * WNUM) return;
  int n = tid % WNUM;
  int lq = tid / WNUM;           // l*4 + quad
  int quad = lq & 3, l = lq >> 2;
  const float* src = w3g + (size_t)l * 64 * WNUM + n;
  int idx = n >> 4, L = n & 15;
  _Float16* dst = w3h + ((size_t)(l * 208 + idx) * 2) * 512 + (quad*16 + L) * 8;
  half8 h0, h1;
  #pragma unroll
  for (int j = 0; j < 8; j++) {
    h0[j] = (_Float16)src[(size_t)(quad*8 + j) * WNUM];
    h1[j] = (_Float16)src[(size_t)(32 + quad*8 + j) * WNUM];
  }
  *(half8*)(dst)       = h0;
  *(half8*)(dst + 512) = h1;
}

// ---------------- embed ----------------
__global__ void embed_kernel(const float* __restrict__ x, const float* __restrict__ ew,
                             float* __restrict__ h) {
  int idx = blockIdx.x * 256 + threadIdx.x;
  if (idx >= NN * 80) return;
  int n = idx / 80, c = idx % 80;
  float v = 0.0f;
  if (c < 32) {
    #pragma unroll
    for (int j = 0; j < 16; j++) v += x[n*16 + j] * ew[j*32 + c];
    v *= 0.25f;
  }
  h[idx] = v;
}

// ---------------- fused: radial MLP (f16 out) + node linears ----------------
#define NB_R (NE/4)
#define NB_N ((NN*160 + 255)/256)
__global__ void rn_fused_kernel(const float* __restrict__ egeo,
                                const float* __restrict__ w1, const float* __restrict__ b1,
                                const float* __restrict__ w2, const float* __restrict__ b2,
                                _Float16* __restrict__ f_h,
                                const float* __restrict__ h,
                                const float* __restrict__ lws, const float* __restrict__ lwv,
                                const float* __restrict__ sws, const float* __restrict__ swv,
                                float* __restrict__ hx, float* __restrict__ xself, int l) {
  __shared__ float h1[4][64];
  if (blockIdx.x < NB_R) {
    // radial MLP: 4 edges per block
    int ty = threadIdx.x >> 6, dk = threadIdx.x & 63;
    int e = blockIdx.x * 4 + ty;
    const float* w1l = w1 + (size_t)l * 8 * 64;
    const float* w2l = w2 + (size_t)l * 64 * 64;
    float acc = b1[l*64 + dk];
    const float* rb = egeo + (size_t)e * 20 + 12;
    #pragma unroll
    for (int j = 0; j < 8; j++) acc += rb[j] * w1l[j*64 + dk];
    h1[ty][dk] = silu_f(acc);
    __syncthreads();
    float acc2 = b2[l*64 + dk];
    #pragma unroll 8
    for (int j = 0; j < 64; j++) acc2 += h1[ty][j] * w2l[j*64 + dk];
    f_h[(size_t)e*64 + dk] = (_Float16)silu_f(acc2);
  } else {
    int idx = (blockIdx.x - NB_R) * 256 + threadIdx.x;
    if (idx >= NN * 160) return;
    int which = (idx >= NN * 80) ? 1 : 0;
    int r = which ? idx - NN*80 : idx;
    int n = r / 80, c = r % 80;
    const float* Ws = (which ? sws : lws) + (size_t)l * 1024;
    const float* Wv = (which ? swv : lwv) + (size_t)l * 256;
    float v = 0.0f;
    if (c < 32) {
      #pragma unroll 8
      for (int u = 0; u < 32; u++) v += h[n*80 + u] * Ws[u*32 + c];
      v *= 0.17677669529663687f;
    } else {
      int oc = c - 32, wch = oc / 3, i = oc % 3;
      #pragma unroll
      for (int u = 0; u < 16; u++) v += h[n*80 + 32 + u*3 + i] * Wv[u*16 + wch];
      v *= 0.25f;
    }
    (which ? xself : hx)[n*80 + c] = v;
  }
}

// ---------------- fused MFMA weight-GEMM (f16) + tensor product -> msg ----------------
__launch_bounds__(256, 4)
__global__ void edge_msg_kernel(const int* __restrict__ ei, const float* __restrict__ egeo,
                                const _Float16* __restrict__ f_h,
                                const float* __restrict__ hx,
                                const _Float16* __restrict__ w3h,
                                const float* __restrict__ b3g,
                                float* __restrict__ msg, int l) {
  __shared__ float sT[32][64];             // s[u][e]
  __shared__ float p2T[16][64];            // p2[u][e]
  __shared__ float q3T[48][64];            // s[u]*y1[i]
  __shared__ float vT[48][64];             // v[u*3+i][e]
  __shared__ float q5T[48][64];            // sqrt(3/5)*v@Ay

  const int t = threadIdx.x;
  const int e0 = blockIdx.x * 64;
  const float* b3l = b3g + (size_t)l * WNUM;

  // ---- prologue: gather hx[src] into transposed LDS ----
  for (int idx = t; idx < 64*80; idx += 256) {
    int e = idx / 80, c = idx % 80;
    int src = ei[e0 + e];
    float val = hx[(size_t)src*80 + c];
    if (c < 32) sT[c][e] = val; else vT[c-32][e] = val;
  }
  __syncthreads();
  for (int idx = t; idx < 64*16; idx += 256) {
    int u = idx >> 6, e = idx & 63;
    const float* g = &egeo[(size_t)(e0+e)*20];
    float a = vT[u*3][e]*g[0] + vT[u*3+1][e]*g[1] + vT[u*3+2][e]*g[2];
    p2T[u][e] = a * 0.5773502691896258f;
  }
  for (int idx = t; idx < 64*48; idx += 256) {
    int o = idx >> 6, e = idx & 63;
    int u = o / 3, jj = o % 3;
    const float* g = &egeo[(size_t)(e0+e)*20];
    q3T[o][e] = sT[u][e] * g[jj];
    float a = vT[u*3][e]*g[3+jj] + vT[u*3+1][e]*g[6+jj] + vT[u*3+2][e]*g[9+jj];
    q5T[o][e] = a * 0.7745966692414834f;
  }

  const int wv = t >> 6, lane = t & 63, L = lane & 15, quad = lane >> 4;
  const int eA = e0 + wv*16 + L;          // A-operand row edge (global)
  const int eloc = wv*16 + quad*4;        // C-operand row-base edge (block-local)
  const int eq = e0 + eloc;               // C-operand row-base edge (global)

  // A fragments (registers, once per block)
  const half8* fh = (const half8*)(f_h + (size_t)eA*64);
  half8 Ah0 = fh[quad], Ah1 = fh[4 + quad];
  __syncthreads();   // factor LDS ready

  f32x4 ms0 = {0,0,0,0}, ms1 = {0,0,0,0}, ms2 = {0,0,0,0};
  f32x4 mv0 = {0,0,0,0}, mv1 = {0,0,0,0}, mv2 = {0,0,0,0};

  const _Float16* wb = w3h + (size_t)l * 208 * 1024 + lane * 8;
  // 2-deep register pipeline
  half8 pb0[2], pb1[2]; float pbs[2];
  pb0[0] = *(const half8*)(wb);
  pb1[0] = *(const half8*)(wb + 512);
  pbs[0] = b3l[L];
  pb0[1] = *(const half8*)(wb + 1024);
  pb1[1] = *(const half8*)(wb + 1536);
  pbs[1] = b3l[16 + L];

#define STEP(SLOT, IDX)                                                          \
  do {                                                                           \
    half8 B0 = pb0[SLOT], B1 = pb1[SLOT];                                        \
    float bb = pbs[SLOT];                                                        \
    if ((IDX) + 2 < 208) {                                                       \
      const _Float16* wn = wb + (size_t)((IDX) + 2) * 1024;                      \
      pb0[SLOT] = *(const half8*)(wn);                                           \
      pb1[SLOT] = *(const half8*)(wn + 512);                                     \
      pbs[SLOT] = b3l[((IDX) + 2) * 16 + L];                                     \
    }                                                                            \
    f32x4 acc = {bb, bb, bb, bb};                                                \
    acc = __builtin_amdgcn_mfma_f32_16x16x32_f16(Ah0, B0, acc, 0, 0, 0);         \
    acc = __builtin_amdgcn_mfma_f32_16x16x32_f16(Ah1, B1, acc, 0, 0, 0);         \
    const int cb = (IDX) << 4;                                                   \
    if (cb < 1536) {                                                             \
      int u = cb / 48, j = (cb % 48) >> 4;                                       \
      f32x4 fac = *(const f32x4*)&sT[u][eloc];                                   \
      if (j == 0) ms0 += fac*acc; else if (j == 1) ms1 += fac*acc; else ms2 += fac*acc; \
    } else if (cb < 2304) {                                                      \
      int u = (cb - 1536) / 48, j = ((cb - 1536) % 48) >> 4;                     \
      f32x4 fac = *(const f32x4*)&p2T[u][eloc];                                  \
      if (j == 0) ms0 += fac*acc; else if (j == 1) ms1 += fac*acc; else ms2 += fac*acc; \
    } else if (cb < 2816) {                                                      \
      int u = (cb - 2304) >> 4;                                                  \
      mv0 += *(const f32x4*)&q3T[u*3+0][eloc] * acc;                             \
      mv1 += *(const f32x4*)&q3T[u*3+1][eloc] * acc;                             \
      mv2 += *(const f32x4*)&q3T[u*3+2][eloc] * acc;                             \
    } else if (cb < 3072) {                                                      \
      int u = (cb - 2816) >> 4;                                                  \
      mv0 += *(const f32x4*)&vT[u*3+0][eloc] * acc;                              \
      mv1 += *(const f32x4*)&vT[u*3+1][eloc] * acc;                              \
      mv2 += *(const f32x4*)&vT[u*3+2][eloc] * acc;                              \
    } else {                                                                     \
      int u = (cb - 3072) >> 4;                                                  \
      mv0 += *(const f32x4*)&q5T[u*3+0][eloc] * acc;                             \
      mv1 += *(const f32x4*)&q5T[u*3+1][eloc] * acc;                             \
      mv2 += *(const f32x4*)&q5T[u*3+2][eloc] * acc;                             \
    }                                                                            \
  } while (0)

  for (int idx = 0; idx < 208; idx += 2) {
    STEP(0, idx);
    STEP(1, idx + 1);
  }
#undef STEP

  // epilogue: scaled write of msg
  const float S48 = 0.14433756729740645f;  // 1/sqrt(48)
  const float S64 = 0.125f;                // 1/sqrt(64)
  #pragma unroll
  for (int r = 0; r < 4; ++r) {
    float* mp = msg + (size_t)(eq + r)*96;
    mp[L]        = ms0[r] * S48;
    mp[16 + L]   = ms1[r] * S48;
    mp[32 + L]   = ms2[r] * S48;
    mp[48 + 3*L]     = mv0[r] * S64;
    mp[48 + 3*L + 1] = mv1[r] * S64;
    mp[48 + 3*L + 2] = mv2[r] * S64;
  }
}

// ---------------- fused CSR gather + node update: 2 nodes per block ----------------
__global__ void agg_update_kernel(const float* __restrict__ msg, const int* __restrict__ offs,
                                  const int* __restrict__ eidx,
                                  const float* __restrict__ xself, float* __restrict__ h) {
  __shared__ float sagg[2][96];
  int t = threadIdx.x;
  int half = t >> 7, tt = t & 127;
  int n = blockIdx.x * 2 + half;
  if (tt < 96) {
    int b = offs[n], e = offs[n+1];
    float acc = 0.0f;
    for (int j = b; j < e; ++j) acc += msg[(size_t)eidx[j]*96 + tt];
    sagg[half][tt] = acc * 0.20412414523193154f;   // 1/sqrt(24)
  }
  __syncthreads();
  if (tt < 80) {
    float a;
    if (tt < 32) {
      a = silu_f(sagg[half][tt]);
    } else {
      int oc = tt - 32, wch = oc / 3;
      a = sagg[half][48 + oc] * sigm_f(sagg[half][32 + wch]);
    }
    h[(size_t)n*80 + tt] = h[(size_t)n*80 + tt] + xself[(size_t)n*80 + tt] + a;
  }
}

// ---------------- final projection ----------------
__global__ void proj_kernel(const float* __restrict__ h, const float* __restrict__ pw,
                            float* __restrict__ out) {
  int idx = blockIdx.x * 256 + threadIdx.x;
  if (idx >= NN * 32) return;
  int n = idx / 32, c = idx % 32;
  float acc = 0.0f;
  #pragma unroll 8
  for (int u = 0; u < 32; u++) acc += h[n*80 + u] * pw[u*32 + c];
  out[idx] = acc * 0.17677669529663687f;
}

extern "C" void kernel_launch(void* const* d_in, const int* in_sizes, int n_in,
                              void* d_out, int out_size, void* d_ws, size_t ws_size,
                              hipStream_t stream) {
  const float* x       = (const float*)d_in[0];
  const float* pos     = (const float*)d_in[1];
  const int*   ei      = (const int*)  d_in[2];
  const float* embed_w = (const float*)d_in[3];
  const float* proj_w  = (const float*)d_in[4];
  const float* lin_ws  = (const float*)d_in[5];
  const float* lin_wv  = (const float*)d_in[6];
  const float* sc_ws   = (const float*)d_in[7];
  const float* sc_wv   = (const float*)d_in[8];
  const float* mlp_w1  = (const float*)d_in[9];
  const float* mlp_b1  = (const float*)d_in[10];
  const float* mlp_w2  = (const float*)d_in[11];
  const float* mlp_b2  = (const float*)d_in[12];
  const float* mlp_w3  = (const float*)d_in[13];
  const float* mlp_b3  = (const float*)d_in[14];
  float* out = (float*)d_out;

  float* ws    = (float*)d_ws;
  float* egeo  = ws;                          // NE*20
  float* h     = egeo  + (size_t)NE*20;       // NN*80
  float* hx    = h     + (size_t)NN*80;       // NN*80
  float* xself = hx    + (size_t)NN*80;       // NN*80
  float* msg   = xself + (size_t)NN*80;       // NE*96
  _Float16* f_h = (_Float16*)(msg + (size_t)NE*96);   // NE*64 f16
  _Float16* w3h = f_h + (size_t)NE*64;                // 4*208*1024 f16
  int* cnt    = (int*)(w3h + (size_t)4*208*1024);     // NN
  int* offs   = cnt + NN;                     // NN+1
  int* cursor = offs + NN + 1;                // NN
  int* eidxb  = cursor + NN;                  // NE

  hipMemsetAsync(cnt, 0, NN*sizeof(int), stream);
  geom_kernel<<<(NE + 255)/256, 256, 0, stream>>>(pos, ei, egeo, cnt);
  scan_kernel<<<1, 256, 0, stream>>>(cnt, offs, cursor);
  scatter_kernel<<<NE/256, 256, 0, stream>>>(ei, cursor, eidxb);
  conv_w3_kernel<<<(16*WNUM + 255)/256, 256, 0, stream>>>(mlp_w3, w3h);
  embed_kernel<<<(NN*80 + 255)/256, 256, 0, stream>>>(x, embed_w, h);

  for (int l = 0; l < 4; l++) {
    rn_fused_kernel<<<NB_R + NB_N, 256, 0, stream>>>(egeo, mlp_w1, mlp_b1, mlp_w2, mlp_b2,
                                                     f_h, h, lin_ws, lin_wv, sc_ws, sc_wv,
                                                     hx, xself, l);
    edge_msg_kernel<<<NE/64, 256, 0, stream>>>(ei, egeo, f_h, hx, w3h, mlp_b3, msg, l);
    agg_update_kernel<<<NN/2, 256, 0, stream>>>(msg, offs, eidxb, xself, h);
  }
  proj_kernel<<<(NN*32 + 255)/256, 256, 0, stream>>>(h, proj_w, out);
}

// Round 6
// 647.618 us; speedup vs baseline: 5.6098x; 1.0645x over previous
//
#include <hip/hip_runtime.h>
#include <math.h>

#define NN 2048
#define NE 49152
#define WNUM 3328

typedef __attribute__((ext_vector_type(8))) _Float16 half8;
typedef __attribute__((ext_vector_type(4))) float f32x4;

__device__ __forceinline__ float silu_f(float x){ return x / (1.0f + expf(-x)); }
__device__ __forceinline__ float sigm_f(float x){ return 1.0f / (1.0f + expf(-x)); }

// ---------------- edge geometry: y1(3), Ay(9), rbf(8) -> egeo stride 20; + dst histogram ----
__global__ void geom_kernel(const float* __restrict__ pos, const int* __restrict__ ei,
                            float* __restrict__ egeo, int* __restrict__ cnt) {
  int e = blockIdx.x * 256 + threadIdx.x;
  if (e >= NE) return;
  int s = ei[e], d = ei[NE + e];
  atomicAdd(&cnt[d], 1);
  float rx = pos[d*3+0] - pos[s*3+0];
  float ry = pos[d*3+1] - pos[s*3+1];
  float rz = pos[d*3+2] - pos[s*3+2];
  float r = sqrtf(rx*rx + ry*ry + rz*rz);
  r = fmaxf(r, 1e-6f);
  float x = rx / r, y = ry / r, z = rz / r;
  const float s3 = 1.7320508075688772f;
  const float c15 = 3.872983346207417f;
  float y2_0 = c15 * x * y;
  float y2_1 = c15 * y * z;
  float y2_2 = 1.118033988749895f * (3.0f*z*z - 1.0f);
  float y2_3 = c15 * x * z;
  float y2_4 = 1.9364916731037085f * (x*x - y*y);
  const float q2 = 0.7071067811865476f;
  const float q6 = 0.4082482904638631f;
  float* g = egeo + (size_t)e * 20;
  g[0] = s3 * x; g[1] = s3 * y; g[2] = s3 * z;
  g[3+0] = -q6*y2_2 + q2*y2_4;
  g[3+1] =  q2*y2_0;
  g[3+2] =  q2*y2_3;
  g[3+3] =  q2*y2_0;
  g[3+4] = -q6*y2_2 - q2*y2_4;
  g[3+5] =  q2*y2_1;
  g[3+6] =  q2*y2_3;
  g[3+7] =  q2*y2_1;
  g[3+8] =  2.0f*q6*y2_2;
  float u = r / 6.0f;
  float fc = 0.0f;
  if (u < 1.0f) {
    float u2=u*u, u3=u2*u, u6=u3*u3, u7=u6*u, u8=u7*u;
    fc = 1.0f - 28.0f*u6 + 48.0f*u7 - 21.0f*u8;
  }
  const float pref = 0.5773502691896258f;
  const float pi6 = 0.5235987755982988f;
  #pragma unroll
  for (int n = 1; n <= 8; n++) {
    g[12 + n - 1] = pref * sinf((float)n * pi6 * r) / r * fc;
  }
}

// ---------------- CSR scan ----------------
__global__ void scan_kernel(const int* __restrict__ cnt, int* __restrict__ offs,
                            int* __restrict__ cursor) {
  __shared__ int part[256];
  int t = threadIdx.x;
  int local[8];
  int s = 0;
  #pragma unroll
  for (int j = 0; j < 8; j++) { local[j] = s; s += cnt[t*8 + j]; }
  part[t] = s;
  __syncthreads();
  for (int off = 1; off < 256; off <<= 1) {
    int v = part[t];
    int add = (t >= off) ? part[t - off] : 0;
    __syncthreads();
    part[t] = v + add;
    __syncthreads();
  }
  int excl = (t == 0) ? 0 : part[t-1];
  #pragma unroll
  for (int j = 0; j < 8; j++) {
    int o = excl + local[j];
    offs[t*8 + j] = o;
    cursor[t*8 + j] = o;
  }
  if (t == 255) offs[2048] = part[255];
}

__global__ void scatter_kernel(const int* __restrict__ ei, int* __restrict__ cursor,
                               int* __restrict__ eidx) {
  int e = blockIdx.x * 256 + threadIdx.x;
  if (e >= NE) return;
  int d = ei[NE + e];
  int p = atomicAdd(&cursor[d], 1);
  eidx[p] = e;
}

// ---------------- W3 -> f16, MFMA-B-fragment-ordered ----------------
// w3h[((l*208 + idx)*2 + plane)*512 + (quad*16+L)*8 + j]
__global__ void conv_w3_kernel(const float* __restrict__ w3g, _Float16* __restrict__ w3h) {
  int tid = blockIdx.x * 256 + threadIdx.x;
  if (tid >= 16 * WNUM) return;
  int n = tid % WNUM;
  int lq = tid / WNUM;           // l*4 + quad
  int quad = lq & 3, l = lq >> 2;
  const float* src = w3g + (size_t)l * 64 * WNUM + n;
  int idx = n >> 4, L = n & 15;
  _Float16* dst = w3h + ((size_t)(l * 208 + idx) * 2) * 512 + (quad*16 + L) * 8;
  half8 h0, h1;
  #pragma unroll
  for (int j = 0; j < 8; j++) {
    h0[j] = (_Float16)src[(size_t)(quad*8 + j) * WNUM];
    h1[j] = (_Float16)src[(size_t)(32 + quad*8 + j) * WNUM];
  }
  *(half8*)(dst)       = h0;
  *(half8*)(dst + 512) = h1;
}

// ---------------- embed ----------------
__global__ void embed_kernel(const float* __restrict__ x, const float* __restrict__ ew,
                             float* __restrict__ h) {
  int idx = blockIdx.x * 256 + threadIdx.x;
  if (idx >= NN * 80) return;
  int n = idx / 80, c = idx % 80;
  float v = 0.0f;
  if (c < 32) {
    #pragma unroll
    for (int j = 0; j < 16; j++) v += x[n*16 + j] * ew[j*32 + c];
    v *= 0.25f;
  }
  h[idx] = v;
}

// ---------------- fused: radial MLP (f16 out) + node linears ----------------
#define NB_R (NE/4)
#define NB_N ((NN*160 + 255)/256)
__global__ void rn_fused_kernel(const float* __restrict__ egeo,
                                const float* __restrict__ w1, const float* __restrict__ b1,
                                const float* __restrict__ w2, const float* __restrict__ b2,
                                _Float16* __restrict__ f_h,
                                const float* __restrict__ h,
                                const float* __restrict__ lws, const float* __restrict__ lwv,
                                const float* __restrict__ sws, const float* __restrict__ swv,
                                float* __restrict__ hx, float* __restrict__ xself, int l) {
  __shared__ float h1[4][64];
  if (blockIdx.x < NB_R) {
    int ty = threadIdx.x >> 6, dk = threadIdx.x & 63;
    int e = blockIdx.x * 4 + ty;
    const float* w1l = w1 + (size_t)l * 8 * 64;
    const float* w2l = w2 + (size_t)l * 64 * 64;
    float acc = b1[l*64 + dk];
    const float* rb = egeo + (size_t)e * 20 + 12;
    #pragma unroll
    for (int j = 0; j < 8; j++) acc += rb[j] * w1l[j*64 + dk];
    h1[ty][dk] = silu_f(acc);
    __syncthreads();
    float acc2 = b2[l*64 + dk];
    #pragma unroll 8
    for (int j = 0; j < 64; j++) acc2 += h1[ty][j] * w2l[j*64 + dk];
    f_h[(size_t)e*64 + dk] = (_Float16)silu_f(acc2);
  } else {
    int idx = (blockIdx.x - NB_R) * 256 + threadIdx.x;
    if (idx >= NN * 160) return;
    int which = (idx >= NN * 80) ? 1 : 0;
    int r = which ? idx - NN*80 : idx;
    int n = r / 80, c = r % 80;
    const float* Ws = (which ? sws : lws) + (size_t)l * 1024;
    const float* Wv = (which ? swv : lwv) + (size_t)l * 256;
    float v = 0.0f;
    if (c < 32) {
      #pragma unroll 8
      for (int u = 0; u < 32; u++) v += h[n*80 + u] * Ws[u*32 + c];
      v *= 0.17677669529663687f;
    } else {
      int oc = c - 32, wch = oc / 3, i = oc % 3;
      #pragma unroll
      for (int u = 0; u < 16; u++) v += h[n*80 + 32 + u*3 + i] * Wv[u*16 + wch];
      v *= 0.25f;
    }
    (which ? xself : hx)[n*80 + c] = v;
  }
}

// ---------------- fused MFMA weight-GEMM (f16) + tensor product -> msg ----------------
// Wave = (edge-half h, col-half c): 2 edge-groups x 104 idx each. Per idx:
// 2 B-loads feed 4 MFMAs + 2 contractions. W3 read 2x per block (was 4x).
// ms partials reduced across col-halves via LDS pool overlaid on q3T post-loop.
__launch_bounds__(256, 3)
__global__ void edge_msg_kernel(const int* __restrict__ ei, const float* __restrict__ egeo,
                                const _Float16* __restrict__ f_h,
                                const float* __restrict__ hx,
                                const _Float16* __restrict__ w3h,
                                const float* __restrict__ b3g,
                                float* __restrict__ msg, int l) {
  __shared__ float sT[32][64];             // s[u][e]
  __shared__ float p2T[16][64];            // p2[u][e]
  __shared__ float q3T[48][64];            // s[u]*y1[i]  (reused as ms-pool post-loop)
  __shared__ float vT[48][64];             // v[u*3+i][e]
  __shared__ float q5T[48][64];            // sqrt(3/5)*v@Ay

  const int t = threadIdx.x;
  const int e0 = blockIdx.x * 64;
  const float* b3l = b3g + (size_t)l * WNUM;

  // ---- prologue: gather hx[src] into transposed LDS ----
  for (int idx = t; idx < 64*80; idx += 256) {
    int e = idx / 80, c = idx % 80;
    int src = ei[e0 + e];
    float val = hx[(size_t)src*80 + c];
    if (c < 32) sT[c][e] = val; else vT[c-32][e] = val;
  }
  __syncthreads();
  for (int idx = t; idx < 64*16; idx += 256) {
    int u = idx >> 6, e = idx & 63;
    const float* g = &egeo[(size_t)(e0+e)*20];
    float a = vT[u*3][e]*g[0] + vT[u*3+1][e]*g[1] + vT[u*3+2][e]*g[2];
    p2T[u][e] = a * 0.5773502691896258f;
  }
  for (int idx = t; idx < 64*48; idx += 256) {
    int o = idx >> 6, e = idx & 63;
    int u = o / 3, jj = o % 3;
    const float* g = &egeo[(size_t)(e0+e)*20];
    q3T[o][e] = sT[u][e] * g[jj];
    float a = vT[u*3][e]*g[3+jj] + vT[u*3+1][e]*g[6+jj] + vT[u*3+2][e]*g[9+jj];
    q5T[o][e] = a * 0.7745966692414834f;
  }

  const int wv = t >> 6, lane = t & 63, L = lane & 15, quad = lane >> 4;
  const int h = wv >> 1;          // edge half (0/1): edges h*32 .. h*32+31
  const int cpart = wv & 1;       // column half (0/1): idx cpart*104 .. +103
  const int el0 = h*32 + quad*4;  // group-0 C row base (block-local)
  const int el1 = el0 + 16;       // group-1

  // A fragments: 2 edge-groups
  const half8* fA0 = (const half8*)(f_h + (size_t)(e0 + h*32 + L)*64);
  const half8* fA1 = (const half8*)(f_h + (size_t)(e0 + h*32 + 16 + L)*64);
  half8 A00 = fA0[quad], A01 = fA0[4 + quad];
  half8 A10 = fA1[quad], A11 = fA1[4 + quad];
  __syncthreads();   // factor LDS ready

  f32x4 ms00={0,0,0,0}, ms01={0,0,0,0}, ms02={0,0,0,0};
  f32x4 ms10={0,0,0,0}, ms11={0,0,0,0}, ms12={0,0,0,0};
  f32x4 mv00={0,0,0,0}, mv01={0,0,0,0}, mv02={0,0,0,0};
  f32x4 mv10={0,0,0,0}, mv11={0,0,0,0}, mv12={0,0,0,0};

  const int lo = cpart * 104, hi = lo + 104;
  const _Float16* wb = w3h + (size_t)l * 208 * 1024 + lane * 8;

  // 4-deep register pipeline
  half8 pb0[4], pb1[4]; float pbs[4];
  #pragma unroll
  for (int s = 0; s < 4; s++) {
    const _Float16* wn = wb + (size_t)(lo + s) * 1024;
    pb0[s] = *(const half8*)(wn);
    pb1[s] = *(const half8*)(wn + 512);
    pbs[s] = b3l[(lo + s) * 16 + L];
  }

#define STEP(SLOT, I)                                                            \
  do {                                                                           \
    half8 B0 = pb0[SLOT], B1 = pb1[SLOT];                                        \
    float bb = pbs[SLOT];                                                        \
    if ((I) + 4 < hi) {                                                          \
      const _Float16* wn = wb + (size_t)((I) + 4) * 1024;                        \
      pb0[SLOT] = *(const half8*)(wn);                                           \
      pb1[SLOT] = *(const half8*)(wn + 512);                                     \
      pbs[SLOT] = b3l[((I) + 4) * 16 + L];                                       \
    }                                                                            \
    f32x4 a0 = {bb, bb, bb, bb}, a1 = {bb, bb, bb, bb};                          \
    a0 = __builtin_amdgcn_mfma_f32_16x16x32_f16(A00, B0, a0, 0, 0, 0);           \
    a0 = __builtin_amdgcn_mfma_f32_16x16x32_f16(A01, B1, a0, 0, 0, 0);           \
    a1 = __builtin_amdgcn_mfma_f32_16x16x32_f16(A10, B0, a1, 0, 0, 0);           \
    a1 = __builtin_amdgcn_mfma_f32_16x16x32_f16(A11, B1, a1, 0, 0, 0);           \
    const int cb = (I) << 4;                                                     \
    if (cb < 1536) {                                                             \
      int u = cb / 48, j = (cb % 48) >> 4;                                       \
      f32x4 f0 = *(const f32x4*)&sT[u][el0];                                     \
      f32x4 f1 = *(const f32x4*)&sT[u][el1];                                     \
      if (j == 0)      { ms00 += f0*a0; ms10 += f1*a1; }                         \
      else if (j == 1) { ms01 += f0*a0; ms11 += f1*a1; }                         \
      else             { ms02 += f0*a0; ms12 += f1*a1; }                         \
    } else if (cb < 2304) {                                                      \
      int u = (cb - 1536) / 48, j = ((cb - 1536) % 48) >> 4;                     \
      f32x4 f0 = *(const f32x4*)&p2T[u][el0];                                    \
      f32x4 f1 = *(const f32x4*)&p2T[u][el1];                                    \
      if (j == 0)      { ms00 += f0*a0; ms10 += f1*a1; }                         \
      else if (j == 1) { ms01 += f0*a0; ms11 += f1*a1; }                         \
      else             { ms02 += f0*a0; ms12 += f1*a1; }                         \
    } else if (cb < 2816) {                                                      \
      int u = (cb - 2304) >> 4;                                                  \
      mv00 += *(const f32x4*)&q3T[u*3+0][el0] * a0;                              \
      mv01 += *(const f32x4*)&q3T[u*3+1][el0] * a0;                              \
      mv02 += *(const f32x4*)&q3T[u*3+2][el0] * a0;                              \
      mv10 += *(const f32x4*)&q3T[u*3+0][el1] * a1;                              \
      mv11 += *(const f32x4*)&q3T[u*3+1][el1] * a1;                              \
      mv12 += *(const f32x4*)&q3T[u*3+2][el1] * a1;                              \
    } else if (cb < 3072) {                                                      \
      int u = (cb - 2816) >> 4;                                                  \
      mv00 += *(const f32x4*)&vT[u*3+0][el0] * a0;                               \
      mv01 += *(const f32x4*)&vT[u*3+1][el0] * a0;                               \
      mv02 += *(const f32x4*)&vT[u*3+2][el0] * a0;                               \
      mv10 += *(const f32x4*)&vT[u*3+0][el1] * a1;                               \
      mv11 += *(const f32x4*)&vT[u*3+1][el1] * a1;                               \
      mv12 += *(const f32x4*)&vT[u*3+2][el1] * a1;                               \
    } else {                                                                     \
      int u = (cb - 3072) >> 4;                                                  \
      mv00 += *(const f32x4*)&q5T[u*3+0][el0] * a0;                              \
      mv01 += *(const f32x4*)&q5T[u*3+1][el0] * a0;                              \
      mv02 += *(const f32x4*)&q5T[u*3+2][el0] * a0;                              \
      mv10 += *(const f32x4*)&q5T[u*3+0][el1] * a1;                              \
      mv11 += *(const f32x4*)&q5T[u*3+1][el1] * a1;                              \
      mv12 += *(const f32x4*)&q5T[u*3+2][el1] * a1;                              \
    }                                                                            \
  } while (0)

  for (int i = lo; i < hi; i += 4) {
    STEP(0, i);
    STEP(1, i + 1);
    STEP(2, i + 2);
    STEP(3, i + 3);
  }
#undef STEP

  // ---- cross-col-half reduction of ms via LDS pool (overlaid on dead q3T) ----
  float* pool = &q3T[0][0];   // 64 edges x 48 channels, flat e*48+o
  __syncthreads();            // all loops done; q3T dead
  if (cpart == 0) {
    #pragma unroll
    for (int r = 0; r < 4; ++r) {
      pool[(el0 + r)*48 + L]      = ms00[r];
      pool[(el0 + r)*48 + 16 + L] = ms01[r];
      pool[(el0 + r)*48 + 32 + L] = ms02[r];
      pool[(el1 + r)*48 + L]      = ms10[r];
      pool[(el1 + r)*48 + 16 + L] = ms11[r];
      pool[(el1 + r)*48 + 32 + L] = ms12[r];
    }
  }
  __syncthreads();
  if (cpart == 1) {
    const float S48 = 0.14433756729740645f;  // 1/sqrt(48)
    const float S64 = 0.125f;                // 1/sqrt(64)
    #pragma unroll
    for (int r = 0; r < 4; ++r) {
      int eb = el0 + r;
      float* mp = msg + (size_t)(e0 + eb)*96;
      mp[L]      = (ms00[r] + pool[eb*48 + L])      * S48;
      mp[16 + L] = (ms01[r] + pool[eb*48 + 16 + L]) * S48;
      mp[32 + L] = (ms02[r] + pool[eb*48 + 32 + L]) * S48;
      mp[48 + 3*L]     = mv00[r] * S64;
      mp[48 + 3*L + 1] = mv01[r] * S64;
      mp[48 + 3*L + 2] = mv02[r] * S64;
      eb = el1 + r;
      mp = msg + (size_t)(e0 + eb)*96;
      mp[L]      = (ms10[r] + pool[eb*48 + L])      * S48;
      mp[16 + L] = (ms11[r] + pool[eb*48 + 16 + L]) * S48;
      mp[32 + L] = (ms12[r] + pool[eb*48 + 32 + L]) * S48;
      mp[48 + 3*L]     = mv10[r] * S64;
      mp[48 + 3*L + 1] = mv11[r] * S64;
      mp[48 + 3*L + 2] = mv12[r] * S64;
    }
  }
}

// ---------------- fused CSR gather + node update: 2 nodes per block ----------------
__global__ void agg_update_kernel(const float* __restrict__ msg, const int* __restrict__ offs,
                                  const int* __restrict__ eidx,
                                  const float* __restrict__ xself, float* __restrict__ h) {
  __shared__ float sagg[2][96];
  int t = threadIdx.x;
  int half = t >> 7, tt = t & 127;
  int n = blockIdx.x * 2 + half;
  if (tt < 96) {
    int b = offs[n], e = offs[n+1];
    float acc = 0.0f;
    for (int j = b; j < e; ++j) acc += msg[(size_t)eidx[j]*96 + tt];
    sagg[half][tt] = acc * 0.20412414523193154f;   // 1/sqrt(24)
  }
  __syncthreads();
  if (tt < 80) {
    float a;
    if (tt < 32) {
      a = silu_f(sagg[half][tt]);
    } else {
      int oc = tt - 32, wch = oc / 3;
      a = sagg[half][48 + oc] * sigm_f(sagg[half][32 + wch]);
    }
    h[(size_t)n*80 + tt] = h[(size_t)n*80 + tt] + xself[(size_t)n*80 + tt] + a;
  }
}

// ---------------- final projection ----------------
__global__ void proj_kernel(const float* __restrict__ h, const float* __restrict__ pw,
                            float* __restrict__ out) {
  int idx = blockIdx.x * 256 + threadIdx.x;
  if (idx >= NN * 32) return;
  int n = idx / 32, c = idx % 32;
  float acc = 0.0f;
  #pragma unroll 8
  for (int u = 0; u < 32; u++) acc += h[n*80 + u] * pw[u*32 + c];
  out[idx] = acc * 0.17677669529663687f;
}

extern "C" void kernel_launch(void* const* d_in, const int* in_sizes, int n_in,
                              void* d_out, int out_size, void* d_ws, size_t ws_size,
                              hipStream_t stream) {
  const float* x       = (const float*)d_in[0];
  const float* pos     = (const float*)d_in[1];
  const int*   ei      = (const int*)  d_in[2];
  const float* embed_w = (const float*)d_in[3];
  const float* proj_w  = (const float*)d_in[4];
  const float* lin_ws  = (const float*)d_in[5];
  const float* lin_wv  = (const float*)d_in[6];
  const float* sc_ws   = (const float*)d_in[7];
  const float* sc_wv   = (const float*)d_in[8];
  const float* mlp_w1  = (const float*)d_in[9];
  const float* mlp_b1  = (const float*)d_in[10];
  const float* mlp_w2  = (const float*)d_in[11];
  const float* mlp_b2  = (const float*)d_in[12];
  const float* mlp_w3  = (const float*)d_in[13];
  const float* mlp_b3  = (const float*)d_in[14];
  float* out = (float*)d_out;

  float* ws    = (float*)d_ws;
  float* egeo  = ws;                          // NE*20
  float* h     = egeo  + (size_t)NE*20;       // NN*80
  float* hx    = h     + (size_t)NN*80;       // NN*80
  float* xself = hx    + (size_t)NN*80;       // NN*80
  float* msg   = xself + (size_t)NN*80;       // NE*96
  _Float16* f_h = (_Float16*)(msg + (size_t)NE*96);   // NE*64 f16
  _Float16* w3h = f_h + (size_t)NE*64;                // 4*208*1024 f16
  int* cnt    = (int*)(w3h + (size_t)4*208*1024);     // NN
  int* offs   = cnt + NN;                     // NN+1
  int* cursor = offs + NN + 1;                // NN
  int* eidxb  = cursor + NN;                  // NE

  hipMemsetAsync(cnt, 0, NN*sizeof(int), stream);
  geom_kernel<<<(NE + 255)/256, 256, 0, stream>>>(pos, ei, egeo, cnt);
  scan_kernel<<<1, 256, 0, stream>>>(cnt, offs, cursor);
  scatter_kernel<<<NE/256, 256, 0, stream>>>(ei, cursor, eidxb);
  conv_w3_kernel<<<(16*WNUM + 255)/256, 256, 0, stream>>>(mlp_w3, w3h);
  embed_kernel<<<(NN*80 + 255)/256, 256, 0, stream>>>(x, embed_w, h);

  for (int l = 0; l < 4; l++) {
    rn_fused_kernel<<<NB_R + NB_N, 256, 0, stream>>>(egeo, mlp_w1, mlp_b1, mlp_w2, mlp_b2,
                                                     f_h, h, lin_ws, lin_wv, sc_ws, sc_wv,
                                                     hx, xself, l);
    edge_msg_kernel<<<NE/64, 256, 0, stream>>>(ei, egeo, f_h, hx, w3h, mlp_b3, msg, l);
    agg_update_kernel<<<NN/2, 256, 0, stream>>>(msg, offs, eidxb, xself, h);
  }
  proj_kernel<<<(NN*32 + 255)/256, 256, 0, stream>>>(h, proj_w, out);
}

// Round 7
// 490.229 us; speedup vs baseline: 7.4109x; 1.3211x over previous
//
#include <hip/hip_runtime.h>
#include <math.h>

#define NN 2048
#define NE 49152
#define WNUM 3328

typedef __attribute__((ext_vector_type(8))) _Float16 half8;
typedef __attribute__((ext_vector_type(4))) float f32x4;

__device__ __forceinline__ float silu_f(float x){ return x / (1.0f + expf(-x)); }
__device__ __forceinline__ float sigm_f(float x){ return 1.0f / (1.0f + expf(-x)); }

// ---------------- edge geometry: y1(3), Ay(9), rbf(8) -> egeo stride 20; + dst histogram ----
__global__ void geom_kernel(const float* __restrict__ pos, const int* __restrict__ ei,
                            float* __restrict__ egeo, int* __restrict__ cnt) {
  int e = blockIdx.x * 256 + threadIdx.x;
  if (e >= NE) return;
  int s = ei[e], d = ei[NE + e];
  atomicAdd(&cnt[d], 1);
  float rx = pos[d*3+0] - pos[s*3+0];
  float ry = pos[d*3+1] - pos[s*3+1];
  float rz = pos[d*3+2] - pos[s*3+2];
  float r = sqrtf(rx*rx + ry*ry + rz*rz);
  r = fmaxf(r, 1e-6f);
  float x = rx / r, y = ry / r, z = rz / r;
  const float s3 = 1.7320508075688772f;
  const float c15 = 3.872983346207417f;
  float y2_0 = c15 * x * y;
  float y2_1 = c15 * y * z;
  float y2_2 = 1.118033988749895f * (3.0f*z*z - 1.0f);
  float y2_3 = c15 * x * z;
  float y2_4 = 1.9364916731037085f * (x*x - y*y);
  const float q2 = 0.7071067811865476f;
  const float q6 = 0.4082482904638631f;
  float* g = egeo + (size_t)e * 20;
  g[0] = s3 * x; g[1] = s3 * y; g[2] = s3 * z;
  g[3+0] = -q6*y2_2 + q2*y2_4;
  g[3+1] =  q2*y2_0;
  g[3+2] =  q2*y2_3;
  g[3+3] =  q2*y2_0;
  g[3+4] = -q6*y2_2 - q2*y2_4;
  g[3+5] =  q2*y2_1;
  g[3+6] =  q2*y2_3;
  g[3+7] =  q2*y2_1;
  g[3+8] =  2.0f*q6*y2_2;
  float u = r / 6.0f;
  float fc = 0.0f;
  if (u < 1.0f) {
    float u2=u*u, u3=u2*u, u6=u3*u3, u7=u6*u, u8=u7*u;
    fc = 1.0f - 28.0f*u6 + 48.0f*u7 - 21.0f*u8;
  }
  const float pref = 0.5773502691896258f;
  const float pi6 = 0.5235987755982988f;
  #pragma unroll
  for (int n = 1; n <= 8; n++) {
    g[12 + n - 1] = pref * sinf((float)n * pi6 * r) / r * fc;
  }
}

// ---------------- CSR scan ----------------
__global__ void scan_kernel(const int* __restrict__ cnt, int* __restrict__ offs,
                            int* __restrict__ cursor) {
  __shared__ int part[256];
  int t = threadIdx.x;
  int local[8];
  int s = 0;
  #pragma unroll
  for (int j = 0; j < 8; j++) { local[j] = s; s += cnt[t*8 + j]; }
  part[t] = s;
  __syncthreads();
  for (int off = 1; off < 256; off <<= 1) {
    int v = part[t];
    int add = (t >= off) ? part[t - off] : 0;
    __syncthreads();
    part[t] = v + add;
    __syncthreads();
  }
  int excl = (t == 0) ? 0 : part[t-1];
  #pragma unroll
  for (int j = 0; j < 8; j++) {
    int o = excl + local[j];
    offs[t*8 + j] = o;
    cursor[t*8 + j] = o;
  }
  if (t == 255) offs[2048] = part[255];
}

__global__ void scatter_kernel(const int* __restrict__ ei, int* __restrict__ cursor,
                               int* __restrict__ eidx) {
  int e = blockIdx.x * 256 + threadIdx.x;
  if (e >= NE) return;
  int d = ei[NE + e];
  int p = atomicAdd(&cursor[d], 1);
  eidx[p] = e;
}

// ---------------- W3 -> f16, MFMA-B-fragment-ordered ----------------
// w3h[((l*208 + idx)*2 + plane)*512 + (quad*16+L)*8 + j]
__global__ void conv_w3_kernel(const float* __restrict__ w3g, _Float16* __restrict__ w3h) {
  int tid = blockIdx.x * 256 + threadIdx.x;
  if (tid >= 16 * WNUM) return;
  int n = tid % WNUM;
  int lq = tid / WNUM;           // l*4 + quad
  int quad = lq & 3, l = lq >> 2;
  const float* src = w3g + (size_t)l * 64 * WNUM + n;
  int idx = n >> 4, L = n & 15;
  _Float16* dst = w3h + ((size_t)(l * 208 + idx) * 2) * 512 + (quad*16 + L) * 8;
  half8 h0, h1;
  #pragma unroll
  for (int j = 0; j < 8; j++) {
    h0[j] = (_Float16)src[(size_t)(quad*8 + j) * WNUM];
    h1[j] = (_Float16)src[(size_t)(32 + quad*8 + j) * WNUM];
  }
  *(half8*)(dst)       = h0;
  *(half8*)(dst + 512) = h1;
}

// ---------------- embed ----------------
__global__ void embed_kernel(const float* __restrict__ x, const float* __restrict__ ew,
                             float* __restrict__ h) {
  int idx = blockIdx.x * 256 + threadIdx.x;
  if (idx >= NN * 80) return;
  int n = idx / 80, c = idx % 80;
  float v = 0.0f;
  if (c < 32) {
    #pragma unroll
    for (int j = 0; j < 16; j++) v += x[n*16 + j] * ew[j*32 + c];
    v *= 0.25f;
  }
  h[idx] = v;
}

// ---------------- fused: radial MLP (f16 out, 16 edges/block) + node linears ----------------
#define NB_R (NE/16)
#define NB_N ((NN*160 + 255)/256)
__global__ void rn_fused_kernel(const float* __restrict__ egeo,
                                const float* __restrict__ w1, const float* __restrict__ b1,
                                const float* __restrict__ w2, const float* __restrict__ b2,
                                _Float16* __restrict__ f_h,
                                const float* __restrict__ h,
                                const float* __restrict__ lws, const float* __restrict__ lwv,
                                const float* __restrict__ sws, const float* __restrict__ swv,
                                float* __restrict__ hx, float* __restrict__ xself, int l) {
  __shared__ float h1s[16][64];
  if (blockIdx.x < NB_R) {
    int ty = threadIdx.x >> 6, dk = threadIdx.x & 63;
    int e0b = blockIdx.x * 16 + ty * 4;
    const float* w1l = w1 + (size_t)l * 8 * 64;
    const float* w2l = w2 + (size_t)l * 64 * 64;
    float b1v = b1[l*64 + dk];
    #pragma unroll
    for (int k = 0; k < 4; ++k) {
      const float* rb = egeo + (size_t)(e0b + k) * 20 + 12;
      float acc = b1v;
      #pragma unroll
      for (int j = 0; j < 8; j++) acc += rb[j] * w1l[j*64 + dk];
      h1s[ty*4 + k][dk] = silu_f(acc);
    }
    __syncthreads();
    float b2v = b2[l*64 + dk];
    float o0 = b2v, o1 = b2v, o2 = b2v, o3 = b2v;
    #pragma unroll 8
    for (int j = 0; j < 64; ++j) {
      float w = w2l[j*64 + dk];
      o0 += h1s[ty*4+0][j] * w;
      o1 += h1s[ty*4+1][j] * w;
      o2 += h1s[ty*4+2][j] * w;
      o3 += h1s[ty*4+3][j] * w;
    }
    f_h[(size_t)(e0b+0)*64 + dk] = (_Float16)silu_f(o0);
    f_h[(size_t)(e0b+1)*64 + dk] = (_Float16)silu_f(o1);
    f_h[(size_t)(e0b+2)*64 + dk] = (_Float16)silu_f(o2);
    f_h[(size_t)(e0b+3)*64 + dk] = (_Float16)silu_f(o3);
  } else {
    int idx = (blockIdx.x - NB_R) * 256 + threadIdx.x;
    if (idx >= NN * 160) return;
    int which = (idx >= NN * 80) ? 1 : 0;
    int r = which ? idx - NN*80 : idx;
    int n = r / 80, c = r % 80;
    const float* Ws = (which ? sws : lws) + (size_t)l * 1024;
    const float* Wv = (which ? swv : lwv) + (size_t)l * 256;
    float v = 0.0f;
    if (c < 32) {
      #pragma unroll 8
      for (int u = 0; u < 32; u++) v += h[n*80 + u] * Ws[u*32 + c];
      v *= 0.17677669529663687f;
    } else {
      int oc = c - 32, wch = oc / 3, i = oc % 3;
      #pragma unroll
      for (int u = 0; u < 16; u++) v += h[n*80 + 32 + u*3 + i] * Wv[u*16 + wch];
      v *= 0.25f;
    }
    (which ? xself : hx)[n*80 + c] = v;
  }
}

// ---------------- fused MFMA weight-GEMM (f16) + tensor product -> msg ----------------
// Wave = one 16-edge A-frag group x ALL 208 column-idx (no cross-wave reduction).
// K-loop split into 5 straight-line type-phases with compile-time column offsets:
// B via 4-deep compile-time-slotted register pipeline, bias via LDS + 2-slot regs,
// factor ds_reads hoisted to 1 per u (ms phases), q3 on the fly from sT x y1-regs.
__launch_bounds__(256, 3)
__global__ void edge_msg_kernel(const int* __restrict__ ei, const float* __restrict__ egeo,
                                const _Float16* __restrict__ f_h,
                                const float* __restrict__ hx,
                                const _Float16* __restrict__ w3h,
                                const float* __restrict__ b3g,
                                float* __restrict__ msg, int l) {
  __shared__ float sT[32][64];             // s[u][e]
  __shared__ float p2T[16][64];            // p2[u][e]
  __shared__ float vT[48][64];             // v[u*3+i][e]
  __shared__ float q5T[48][64];            // sqrt(3/5)*v@Ay
  __shared__ float biasL[WNUM];            // b3 for this layer

  const int t = threadIdx.x;
  const int e0 = blockIdx.x * 64;
  const float* b3l = b3g + (size_t)l * WNUM;

  // ---- prologue ----
  for (int i = t; i < WNUM; i += 256) biasL[i] = b3l[i];
  for (int idx = t; idx < 64*80; idx += 256) {
    int e = idx / 80, c = idx % 80;
    int src = ei[e0 + e];
    float val = hx[(size_t)src*80 + c];
    if (c < 32) sT[c][e] = val; else vT[c-32][e] = val;
  }
  __syncthreads();
  for (int idx = t; idx < 64*16; idx += 256) {
    int u = idx >> 6, e = idx & 63;
    const float* g = &egeo[(size_t)(e0+e)*20];
    float a = vT[u*3][e]*g[0] + vT[u*3+1][e]*g[1] + vT[u*3+2][e]*g[2];
    p2T[u][e] = a * 0.5773502691896258f;
  }
  for (int idx = t; idx < 64*48; idx += 256) {
    int o = idx >> 6, e = idx & 63;
    int u = o / 3, jj = o % 3;
    const float* g = &egeo[(size_t)(e0+e)*20];
    float a = vT[u*3][e]*g[3+jj] + vT[u*3+1][e]*g[6+jj] + vT[u*3+2][e]*g[9+jj];
    q5T[o][e] = a * 0.7745966692414834f;
  }

  const int wv = t >> 6, lane = t & 63, L = lane & 15, quad = lane >> 4;
  const int el = wv*16 + quad*4;          // C-operand row base (block-local)
  const int eq = e0 + el;                 // global
  const int eA = e0 + wv*16 + L;          // A-operand row edge

  // A fragments
  const half8* fA = (const half8*)(f_h + (size_t)eA*64);
  half8 Ah0 = fA[quad], Ah1 = fA[4 + quad];

  // per-lane y1 for the 4 owned edges
  f32x4 vy0, vy1, vy2;
  #pragma unroll
  for (int r = 0; r < 4; r++) {
    const float* g = &egeo[(size_t)(eq + r)*20];
    vy0[r] = g[0]; vy1[r] = g[1]; vy2[r] = g[2];
  }
  __syncthreads();   // LDS ready

  f32x4 ms0={0,0,0,0}, ms1={0,0,0,0}, ms2={0,0,0,0};
  f32x4 mv0={0,0,0,0}, mv1={0,0,0,0}, mv2={0,0,0,0};

  const _Float16* wb = w3h + (size_t)l * 208 * 1024 + lane * 8;
  // 4-deep B pipeline (slot = idx & 3, compile-time), 2-slot bias pipeline (idx & 1)
  half8 pb0[4], pb1[4];
  #pragma unroll
  for (int s = 0; s < 4; s++) {
    pb0[s] = *(const half8*)(wb + (size_t)s * 1024);
    pb1[s] = *(const half8*)(wb + (size_t)s * 1024 + 512);
  }
  float bs[2];
  bs[0] = biasL[L];
  bs[1] = biasL[16 + L];

  // GSTEP: UB must be ≡ 0 (mod 4) and even; CO compile-time.
#define GSTEP(UB, CO, ACC)                                                   \
  f32x4 ACC;                                                                 \
  {                                                                          \
    const int _idx = (UB) + (CO);                                            \
    half8 _B0 = pb0[(CO)&3], _B1 = pb1[(CO)&3];                              \
    if (_idx + 4 < 208) {                                                    \
      const _Float16* _wn = wb + (size_t)(_idx + 4) * 1024;                  \
      pb0[(CO)&3] = *(const half8*)(_wn);                                    \
      pb1[(CO)&3] = *(const half8*)(_wn + 512);                              \
    }                                                                        \
    float _bb = bs[(CO)&1];                                                  \
    if (_idx + 2 < 208) bs[(CO)&1] = biasL[(_idx + 2)*16 + L];               \
    ACC = (f32x4){_bb, _bb, _bb, _bb};                                       \
    ACC = __builtin_amdgcn_mfma_f32_16x16x32_f16(Ah0, _B0, ACC, 0, 0, 0);    \
    ACC = __builtin_amdgcn_mfma_f32_16x16x32_f16(Ah1, _B1, ACC, 0, 0, 0);    \
  }

  // ---- type1: idx 0..95, u 0..31, ms ----
  for (int u = 0; u < 32; u += 4) {
    const int UB = u * 3;
    #pragma unroll
    for (int uu = 0; uu < 4; ++uu) {
      f32x4 fac = *(const f32x4*)&sT[u + uu][el];
      GSTEP(UB, uu*3+0, a0); ms0 += fac * a0;
      GSTEP(UB, uu*3+1, a1); ms1 += fac * a1;
      GSTEP(UB, uu*3+2, a2); ms2 += fac * a2;
    }
  }
  // ---- type2: idx 96..143, u 0..15, ms ----
  for (int u = 0; u < 16; u += 4) {
    const int UB = 96 + u * 3;
    #pragma unroll
    for (int uu = 0; uu < 4; ++uu) {
      f32x4 fac = *(const f32x4*)&p2T[u + uu][el];
      GSTEP(UB, uu*3+0, a0); ms0 += fac * a0;
      GSTEP(UB, uu*3+1, a1); ms1 += fac * a1;
      GSTEP(UB, uu*3+2, a2); ms2 += fac * a2;
    }
  }
  // ---- type3: idx 144..175, u 0..31, mv += (s*y1)*acc ----
  for (int u = 0; u < 32; u += 4) {
    const int UB = 144 + u;
    #pragma unroll
    for (int uu = 0; uu < 4; ++uu) {
      f32x4 fac = *(const f32x4*)&sT[u + uu][el];
      GSTEP(UB, uu, a);
      mv0 += (fac * vy0) * a;
      mv1 += (fac * vy1) * a;
      mv2 += (fac * vy2) * a;
    }
  }
  // ---- type4: idx 176..191, u 0..15, mv += v*acc ----
  for (int u = 0; u < 16; u += 4) {
    const int UB = 176 + u;
    #pragma unroll
    for (int uu = 0; uu < 4; ++uu) {
      f32x4 f0 = *(const f32x4*)&vT[(u+uu)*3+0][el];
      f32x4 f1 = *(const f32x4*)&vT[(u+uu)*3+1][el];
      f32x4 f2 = *(const f32x4*)&vT[(u+uu)*3+2][el];
      GSTEP(UB, uu, a);
      mv0 += f0 * a; mv1 += f1 * a; mv2 += f2 * a;
    }
  }
  // ---- type5: idx 192..207, u 0..15, mv += q5*acc ----
  for (int u = 0; u < 16; u += 4) {
    const int UB = 192 + u;
    #pragma unroll
    for (int uu = 0; uu < 4; ++uu) {
      f32x4 f0 = *(const f32x4*)&q5T[(u+uu)*3+0][el];
      f32x4 f1 = *(const f32x4*)&q5T[(u+uu)*3+1][el];
      f32x4 f2 = *(const f32x4*)&q5T[(u+uu)*3+2][el];
      GSTEP(UB, uu, a);
      mv0 += f0 * a; mv1 += f1 * a; mv2 += f2 * a;
    }
  }
#undef GSTEP

  // epilogue: scaled write of msg
  const float S48 = 0.14433756729740645f;  // 1/sqrt(48)
  const float S64 = 0.125f;                // 1/sqrt(64)
  #pragma unroll
  for (int r = 0; r < 4; ++r) {
    float* mp = msg + (size_t)(eq + r)*96;
    mp[L]        = ms0[r] * S48;
    mp[16 + L]   = ms1[r] * S48;
    mp[32 + L]   = ms2[r] * S48;
    mp[48 + 3*L]     = mv0[r] * S64;
    mp[48 + 3*L + 1] = mv1[r] * S64;
    mp[48 + 3*L + 2] = mv2[r] * S64;
  }
}

// ---------------- fused CSR gather + node update: 2 nodes per block ----------------
__global__ void agg_update_kernel(const float* __restrict__ msg, const int* __restrict__ offs,
                                  const int* __restrict__ eidx,
                                  const float* __restrict__ xself, float* __restrict__ h) {
  __shared__ float sagg[2][96];
  int t = threadIdx.x;
  int half = t >> 7, tt = t & 127;
  int n = blockIdx.x * 2 + half;
  if (tt < 96) {
    int b = offs[n], e = offs[n+1];
    float acc = 0.0f, acc2 = 0.0f;
    int j = b;
    for (; j + 1 < e; j += 2) {
      acc  += msg[(size_t)eidx[j]*96 + tt];
      acc2 += msg[(size_t)eidx[j+1]*96 + tt];
    }
    if (j < e) acc += msg[(size_t)eidx[j]*96 + tt];
    sagg[half][tt] = (acc + acc2) * 0.20412414523193154f;   // 1/sqrt(24)
  }
  __syncthreads();
  if (tt < 80) {
    float a;
    if (tt < 32) {
      a = silu_f(sagg[half][tt]);
    } else {
      int oc = tt - 32, wch = oc / 3;
      a = sagg[half][48 + oc] * sigm_f(sagg[half][32 + wch]);
    }
    h[(size_t)n*80 + tt] = h[(size_t)n*80 + tt] + xself[(size_t)n*80 + tt] + a;
  }
}

// ---------------- final projection ----------------
__global__ void proj_kernel(const float* __restrict__ h, const float* __restrict__ pw,
                            float* __restrict__ out) {
  int idx = blockIdx.x * 256 + threadIdx.x;
  if (idx >= NN * 32) return;
  int n = idx / 32, c = idx % 32;
  float acc = 0.0f;
  #pragma unroll 8
  for (int u = 0; u < 32; u++) acc += h[n*80 + u] * pw[u*32 + c];
  out[idx] = acc * 0.17677669529663687f;
}

extern "C" void kernel_launch(void* const* d_in, const int* in_sizes, int n_in,
                              void* d_out, int out_size, void* d_ws, size_t ws_size,
                              hipStream_t stream) {
  const float* x       = (const float*)d_in[0];
  const float* pos     = (const float*)d_in[1];
  const int*   ei      = (const int*)  d_in[2];
  const float* embed_w = (const float*)d_in[3];
  const float* proj_w  = (const float*)d_in[4];
  const float* lin_ws  = (const float*)d_in[5];
  const float* lin_wv  = (const float*)d_in[6];
  const float* sc_ws   = (const float*)d_in[7];
  const float* sc_wv   = (const float*)d_in[8];
  const float* mlp_w1  = (const float*)d_in[9];
  const float* mlp_b1  = (const float*)d_in[10];
  const float* mlp_w2  = (const float*)d_in[11];
  const float* mlp_b2  = (const float*)d_in[12];
  const float* mlp_w3  = (const float*)d_in[13];
  const float* mlp_b3  = (const float*)d_in[14];
  float* out = (float*)d_out;

  float* ws    = (float*)d_ws;
  float* egeo  = ws;                          // NE*20
  float* h     = egeo  + (size_t)NE*20;       // NN*80
  float* hx    = h     + (size_t)NN*80;       // NN*80
  float* xself = hx    + (size_t)NN*80;       // NN*80
  float* msg   = xself + (size_t)NN*80;       // NE*96
  _Float16* f_h = (_Float16*)(msg + (size_t)NE*96);   // NE*64 f16
  _Float16* w3h = f_h + (size_t)NE*64;                // 4*208*1024 f16
  int* cnt    = (int*)(w3h + (size_t)4*208*1024);     // NN
  int* offs   = cnt + NN;                     // NN+1
  int* cursor = offs + NN + 1;                // NN
  int* eidxb  = cursor + NN;                  // NE

  hipMemsetAsync(cnt, 0, NN*sizeof(int), stream);
  geom_kernel<<<(NE + 255)/256, 256, 0, stream>>>(pos, ei, egeo, cnt);
  scan_kernel<<<1, 256, 0, stream>>>(cnt, offs, cursor);
  scatter_kernel<<<NE/256, 256, 0, stream>>>(ei, cursor, eidxb);
  conv_w3_kernel<<<(16*WNUM + 255)/256, 256, 0, stream>>>(mlp_w3, w3h);
  embed_kernel<<<(NN*80 + 255)/256, 256, 0, stream>>>(x, embed_w, h);

  for (int l = 0; l < 4; l++) {
    rn_fused_kernel<<<NB_R + NB_N, 256, 0, stream>>>(egeo, mlp_w1, mlp_b1, mlp_w2, mlp_b2,
                                                     f_h, h, lin_ws, lin_wv, sc_ws, sc_wv,
                                                     hx, xself, l);
    edge_msg_kernel<<<NE/64, 256, 0, stream>>>(ei, egeo, f_h, hx, w3h, mlp_b3, msg, l);
    agg_update_kernel<<<NN/2, 256, 0, stream>>>(msg, offs, eidxb, xself, h);
  }
  proj_kernel<<<(NN*32 + 255)/256, 256, 0, stream>>>(h, proj_w, out);
}